// Round 2
// baseline (1267.865 us; speedup 1.0000x reference)
//
#include <hip/hip_runtime.h>

#define BA 128
#define H 256
#define TH 768
#define NROWS (1024 * BA)
#define LCAP 65536
#define NBUCK 8
#define MT 32
#define AP 264

typedef _Float16 h2_t __attribute__((ext_vector_type(2)));
typedef _Float16 h8_t __attribute__((ext_vector_type(8)));
typedef short s8_t __attribute__((ext_vector_type(8)));
typedef float f4_t __attribute__((ext_vector_type(4)));
typedef unsigned short u16;
typedef u16 us4_t __attribute__((ext_vector_type(4)));
typedef unsigned int u32;
typedef u32 v64u __attribute__((ext_vector_type(64)));

__device__ __forceinline__ float bf2f(u16 u) {
  union { u32 i; float f; } c; c.i = ((u32)u) << 16; return c.f;
}
__device__ __forceinline__ u16 f2bf(float f) {
  union { float f; u32 i; } c; c.f = f;
  u32 r = c.i + 0x7FFFu + ((c.i >> 16) & 1u);
  return (u16)(r >> 16);
}
__device__ __forceinline__ float sigm(float x) {
  float e = __builtin_amdgcn_exp2f(-x * 1.442695040888963f);
  return __builtin_amdgcn_rcpf(1.0f + e);
}
__device__ __forceinline__ float tanh_(float x) {
  float e = __builtin_amdgcn_exp2f(x * 2.885390081777927f);
  return 1.0f - 2.0f * __builtin_amdgcn_rcpf(1.0f + e);
}
__device__ __forceinline__ float ldf(const void* p, bool f32, size_t idx) {
  return f32 ? ((const float*)p)[idx] : bf2f(((const u16*)p)[idx]);
}
__device__ __forceinline__ int ldrst(const void* p, bool isbyte, size_t idx) {
  return isbyte ? (int)((const unsigned char*)p)[idx] : ((const int*)p)[idx];
}
__device__ __forceinline__ float F2(h2_t a, h2_t b, float c) {
#if defined(__has_builtin) && __has_builtin(__builtin_amdgcn_fdot2)
  return __builtin_amdgcn_fdot2(a, b, c, false);
#else
  return c + (float)a[0] * (float)b[0] + (float)a[1] * (float)b[1];
#endif
}

// flags: [0]=ins_f32 [1]=resets_byte [2]=Wh_f32 [3]=Wi_f32
__global__ __launch_bounds__(256) void kdetect(const u32* __restrict__ insw,
                                               const u32* __restrict__ rstw,
                                               const u32* __restrict__ whrw,
                                               const u32* __restrict__ wirw,
                                               int* __restrict__ flags,
                                               int* __restrict__ cnt) {
  __shared__ int c0, c1, c2, c3;
  if (threadIdx.x == 0) { c0 = 0; c1 = 0; c2 = 0; c3 = 0; }
  if (threadIdx.x < NBUCK) cnt[threadIdx.x] = 0;
  __syncthreads();
  if (!(fabsf(bf2f((u16)(insw[threadIdx.x] & 0xFFFFu))) < 1e10f)) atomicAdd(&c0, 1);
  if (!(fabsf(bf2f((u16)(whrw[threadIdx.x] & 0xFFFFu))) < 1e10f)) atomicAdd(&c2, 1);
  if (!(fabsf(bf2f((u16)(wirw[threadIdx.x] & 0xFFFFu))) < 1e10f)) atomicAdd(&c3, 1);
  if (threadIdx.x < 128 && rstw[threadIdx.x] > 1u) atomicAdd(&c1, 1);
  __syncthreads();
  if (threadIdx.x == 0) {
    flags[0] = (c0 > 8) ? 1 : 0;
    flags[1] = (c1 > 0) ? 1 : 0;
    flags[2] = (c2 > 8) ? 1 : 0;
    flags[3] = (c3 > 8) ? 1 : 0;
  }
}

// convert ins -> bf16 (or pass-through)
__global__ __launch_bounds__(256) void kprep(const void* __restrict__ ins,
                                             u16* __restrict__ insb,
                                             const int* __restrict__ flags) {
  bool f32in = flags[0] != 0;
  size_t i0 = ((size_t)blockIdx.x * 256 + threadIdx.x) * 8;
  s8_t v;
  if (f32in) {
    f4_t x0 = *(const f4_t*)((const float*)ins + i0);
    f4_t x1 = *(const f4_t*)((const float*)ins + i0 + 4);
#pragma unroll
    for (int i = 0; i < 4; ++i) v[i] = (short)f2bf(x0[i]);
#pragma unroll
    for (int i = 0; i < 4; ++i) v[4 + i] = (short)f2bf(x1[i]);
  } else {
    v = *(const s8_t*)((const u16*)ins + i0);
  }
  *(s8_t*)(insb + i0) = v;
}

// WT[g][j][k] = W_g[k][j]; g=0..2 (Wi): bf16 for MFMA; g=3..5 (Wh): f16
__global__ __launch_bounds__(256) void ktrans(const void* __restrict__ W0, const void* __restrict__ W1,
                                              const void* __restrict__ W2, const void* __restrict__ W3,
                                              const void* __restrict__ W4, const void* __restrict__ W5,
                                              u16* __restrict__ WT, const int* __restrict__ flags) {
  __shared__ u16 tile[64][65];
  int g = blockIdx.z;
  bool f32in = ((g < 3) ? flags[3] : flags[2]) != 0;
  bool toF16 = (g >= 3);
  const void* srcs[6] = {W0, W1, W2, W3, W4, W5};
  const void* src = srcs[g];
  int k0 = blockIdx.x * 64, j0 = blockIdx.y * 64;
  int tid = threadIdx.x;
#pragma unroll
  for (int p = 0; p < 16; ++p) {
    int e = p * 256 + tid;
    int kr = e >> 6, jc = e & 63;
    size_t idx = (size_t)(k0 + kr) * H + j0 + jc;
    float v = f32in ? ((const float*)src)[idx] : bf2f(((const u16*)src)[idx]);
    u16 bits;
    if (toF16) {
      _Float16 h = (_Float16)v;
      bits = __builtin_bit_cast(u16, h);
    } else {
      bits = f2bf(v);
    }
    tile[kr][jc] = bits;
  }
  __syncthreads();
  u16* dst = WT + (size_t)g * H * H;
#pragma unroll
  for (int p = 0; p < 16; ++p) {
    int e = p * 256 + tid;
    int jr = e >> 6, kc = e & 63;
    dst[(size_t)(j0 + jr) * H + k0 + kc] = tile[kc][jr];
  }
}

// WhB: MFMA-fragment-ordered Wh^T (f16). fragment f=(kk*48+cg)*64+lane holds
// Wh_g^T[col=(cg&15)*16+(lane&15)][k=kk*32+(lane>>4)*8 .. +8], g=cg>>4.
__global__ __launch_bounds__(256) void kswz(const u16* __restrict__ WT, u16* __restrict__ WhB) {
  int f = blockIdx.x * 256 + threadIdx.x;  // 96 blocks * 256 = 24576 fragments
  if (f >= 8 * 48 * 64) return;
  int lane = f & 63;
  int cg = (f >> 6) % 48;
  int kk = (f >> 6) / 48;
  int g = cg >> 4;
  int col = ((cg & 15) << 4) + (lane & 15);
  int k0 = kk * 32 + ((lane >> 4) << 3);
  const u16* src = WT + (size_t)(3 + g) * H * H + (size_t)col * H + k0;
  *(s8_t*)(WhB + (size_t)f * 8) = *(const s8_t*)src;
}

// xproj[m, g*256+j] = ins[m,:] @ W_ig[:,j]  -> bf16
#define LDK 40
__global__ __launch_bounds__(256) void kgemm(const void* __restrict__ ins,
                                             const u16* __restrict__ insb, int use_insb,
                                             int t0, const u16* __restrict__ WT,
                                             u16* __restrict__ C,
                                             const int* __restrict__ flags) {
  __shared__ u16 As[128 * LDK];
  __shared__ u16 Bs[128 * LDK];
  bool f32in = flags[0] != 0;
  int tid = threadIdx.x;
  int row0 = blockIdx.x * 128;
  int col0 = blockIdx.y * 128;
  int gate = col0 >> 8;
  int j0 = col0 & 255;
  const u16* Bg = WT + (size_t)gate * H * H + (size_t)j0 * H;
  size_t abase = (size_t)t0 * BA * H;
  int lane = tid & 63;
  int wave = tid >> 6;
  int r16 = lane & 15;
  int kg = lane >> 4;
  f4_t acc[2][8];
#pragma unroll
  for (int rt = 0; rt < 2; ++rt)
#pragma unroll
    for (int ct = 0; ct < 8; ++ct) acc[rt][ct] = (f4_t)0.0f;

  for (int kk = 0; kk < 8; ++kk) {
    int k0 = kk * 32;
#pragma unroll
    for (int p = 0; p < 2; ++p) {
      int idx = p * 256 + tid;
      int m = idx >> 2;
      int kq = (idx & 3) * 8;
      size_t e = abase + (size_t)(row0 + m) * H + k0 + kq;
      s8_t v;
      if (use_insb) {
        v = *(const s8_t*)(insb + e);
      } else if (f32in) {
        f4_t x0 = *(const f4_t*)((const float*)ins + e);
        f4_t x1 = *(const f4_t*)((const float*)ins + e + 4);
#pragma unroll
        for (int i = 0; i < 4; ++i) v[i] = (short)f2bf(x0[i]);
#pragma unroll
        for (int i = 0; i < 4; ++i) v[4 + i] = (short)f2bf(x1[i]);
      } else {
        v = *(const s8_t*)((const u16*)ins + e);
      }
      *(s8_t*)(As + m * LDK + kq) = v;
    }
#pragma unroll
    for (int p = 0; p < 2; ++p) {
      int idx = p * 256 + tid;
      int n = idx >> 2;
      int kq = (idx & 3) * 8;
      s8_t v = *(const s8_t*)(Bg + (size_t)n * H + k0 + kq);
      *(s8_t*)(Bs + n * LDK + kq) = v;
    }
    __syncthreads();
    s8_t af[2], bf[8];
#pragma unroll
    for (int rt = 0; rt < 2; ++rt)
      af[rt] = *(const s8_t*)(As + (wave * 32 + rt * 16 + r16) * LDK + kg * 8);
#pragma unroll
    for (int ct = 0; ct < 8; ++ct)
      bf[ct] = *(const s8_t*)(Bs + (ct * 16 + r16) * LDK + kg * 8);
#pragma unroll
    for (int rt = 0; rt < 2; ++rt)
#pragma unroll
      for (int ct = 0; ct < 8; ++ct)
        acc[rt][ct] = __builtin_amdgcn_mfma_f32_16x16x32_bf16(af[rt], bf[ct], acc[rt][ct], 0, 0, 0);
    __syncthreads();
  }
#pragma unroll
  for (int rt = 0; rt < 2; ++rt)
#pragma unroll
    for (int ct = 0; ct < 8; ++ct)
#pragma unroll
      for (int r = 0; r < 4; ++r) {
        int grow = row0 + wave * 32 + rt * 16 + kg * 4 + r;
        int gcol = col0 + ct * 16 + r16;
        C[(size_t)grow * TH + gcol] = f2bf(acc[rt][ct][r]);
      }
}

// ---- segment-level machinery ----------------------------------------------
__global__ __launch_bounds__(256) void kdlists(const void* __restrict__ resets,
                                               unsigned char* __restrict__ dbuf,
                                               int* __restrict__ cnt,
                                               u32* __restrict__ list,
                                               const int* __restrict__ flags) {
  bool rbyte = flags[1] != 0;
  int id = blockIdx.x * 256 + threadIdx.x;  // grid 512 x 256 == NROWS
  int t = id >> 7, w = id & 127;
  int d;
  if (ldrst(resets, rbyte, id)) {
    d = 255;  // reset-row marker
  } else {
    int tr = t - 1;
    while (tr >= 0 && !ldrst(resets, rbyte, (size_t)tr * BA + w)) --tr;
    d = t - ((tr >= 0) ? tr : 0);
    if (d > 254) d = 254;
  }
  dbuf[id] = (unsigned char)d;
  int lane = threadIdx.x & 63;
#pragma unroll 1
  for (int s = 0; s < NBUCK; ++s) {
    unsigned long long m = __ballot(d == s);
    if (m) {
      int n = __popcll(m);
      int base = 0;
      if (lane == 0) base = atomicAdd(&cnt[s], n);
      base = __shfl(base, 0, 64);
      if (d == s) {
        int pos = base + (int)__popcll(m & ((1ull << lane) - 1ull));
        if (pos < LCAP) list[(size_t)s * LCAP + pos] = (u32)id;
      }
    }
  }
}

// all reset rows: h_prev = 0 -> pure elementwise from xproj
__global__ __launch_bounds__(256) void kelem(const u16* __restrict__ xproj,
                                             const void* __restrict__ resets,
                                             float* __restrict__ out,
                                             const void* __restrict__ bir, const void* __restrict__ biz,
                                             const void* __restrict__ bin_, const void* __restrict__ bhn,
                                             const int* __restrict__ flags) {
  bool rbyte = flags[1] != 0;
  bool wf32 = flags[2] != 0;
  int j = threadIdx.x;
  float vbir = ldf(bir, wf32, j), vbiz = ldf(biz, wf32, j);
  float vbin = ldf(bin_, wf32, j), vbhn = ldf(bhn, wf32, j);
  for (int i = blockIdx.x; i < NROWS; i += gridDim.x) {
    if (!ldrst(resets, rbyte, i)) continue;
    size_t xb = (size_t)i * TH + j;
    float r = sigm(bf2f(xproj[xb]) + vbir);
    float z = sigm(bf2f(xproj[xb + H]) + vbiz);
    float n = tanh_(bf2f(xproj[xb + 2 * H]) + vbin + r * vbhn);
    out[(size_t)i * H + j] = (1.0f - z) * n;
  }
}

// one d-level: gather h_prev rows into LDS (f16, full K), B direct from L2 in
// fragment order (WhB) -> no B staging, 2 barriers/tile, M=32 tiles.
__global__ __launch_bounds__(512, 4) void kstep(const u16* __restrict__ xproj,
                                                float* __restrict__ out,
                                                const void* __restrict__ h0,
                                                const u16* __restrict__ WhB,
                                                const int* __restrict__ cnt,
                                                const u32* __restrict__ list,
                                                const void* __restrict__ bir, const void* __restrict__ biz,
                                                const void* __restrict__ bin_, const void* __restrict__ bhn,
                                                const int* __restrict__ flags, int s) {
  int cs = cnt[s];
  if (cs <= 0) return;
  bool wf32 = flags[2] != 0;
  __shared__ __align__(16) u16 As[MT * AP];  // f16 h rows, full K=256
  __shared__ int ridS[MT];
  int tid = threadIdx.x;
  int lane = tid & 63;
  int wv = tid >> 6;
  int r16 = lane & 15;
  int kg = lane >> 4;
  int ntiles = (cs + MT - 1) / MT;
  float vb[2][4];
#pragma unroll
  for (int jt = 0; jt < 2; ++jt) {
    int j = wv * 32 + jt * 16 + r16;
    vb[jt][0] = ldf(bir, wf32, j);
    vb[jt][1] = ldf(biz, wf32, j);
    vb[jt][2] = ldf(bin_, wf32, j);
    vb[jt][3] = ldf(bhn, wf32, j);
  }
  const s8_t* WB = (const s8_t*)WhB;  // 16B fragments

  for (int tile = blockIdx.x; tile < ntiles; tile += gridDim.x) {
    __syncthreads();  // As/ridS reuse safe (prev epilogue done)
    {  // stage A: 16 threads/row, 16 f16 elements each
      int i = tid >> 4;
      int seg = tid & 15;
      int idx = tile * MT + i;
      int rid = (idx < cs) ? (int)list[idx] : -1;
      if (seg == 0) ridS[i] = rid;
      u16* dst = As + i * AP + seg * 16;
      if (rid >= 0) {
        if (s == 0) {
#pragma unroll
          for (int q = 0; q < 4; ++q) {
            us4_t hb;
#pragma unroll
            for (int e = 0; e < 4; ++e) {
              _Float16 hh = (_Float16)ldf(h0, wf32, (size_t)rid * H + seg * 16 + q * 4 + e);
              hb[e] = __builtin_bit_cast(u16, hh);
            }
            *(us4_t*)(dst + q * 4) = hb;
          }
        } else {
          const float* src = out + (size_t)(rid - BA) * H + seg * 16;
#pragma unroll
          for (int q = 0; q < 4; ++q) {
            f4_t v = *(const f4_t*)(src + q * 4);
            us4_t hb;
#pragma unroll
            for (int e = 0; e < 4; ++e) {
              _Float16 hh = (_Float16)v[e];
              hb[e] = __builtin_bit_cast(u16, hh);
            }
            *(us4_t*)(dst + q * 4) = hb;
          }
        }
      } else {
        us4_t hz; hz[0] = 0; hz[1] = 0; hz[2] = 0; hz[3] = 0;
#pragma unroll
        for (int q = 0; q < 4; ++q) *(us4_t*)(dst + q * 4) = hz;
      }
    }
    __syncthreads();

    f4_t acc[2][6];
#pragma unroll
    for (int a = 0; a < 2; ++a)
#pragma unroll
      for (int b = 0; b < 6; ++b) acc[a][b] = (f4_t)0.0f;

#pragma unroll
    for (int kk = 0; kk < 8; ++kk) {
      h8_t af[2];
#pragma unroll
      for (int mt = 0; mt < 2; ++mt)
        af[mt] = __builtin_bit_cast(h8_t,
            *(const s8_t*)(As + (mt * 16 + r16) * AP + kk * 32 + kg * 8));
      s8_t bfr[6];
#pragma unroll
      for (int g = 0; g < 3; ++g)
#pragma unroll
        for (int jt = 0; jt < 2; ++jt) {
          int cg = g * 16 + wv * 2 + jt;
          bfr[g * 2 + jt] = WB[(size_t)((kk * 48 + cg) * 64 + lane)];
        }
#pragma unroll
      for (int c = 0; c < 6; ++c)
#pragma unroll
        for (int mt = 0; mt < 2; ++mt)
          acc[mt][c] = __builtin_amdgcn_mfma_f32_16x16x32_f16(
              af[mt], __builtin_bit_cast(h8_t, bfr[c]), acc[mt][c], 0, 0, 0);
    }

    // epilogue: row = mt*16 + kg*4 + r, col = wv*32 + jt*16 + r16
#pragma unroll
    for (int mt = 0; mt < 2; ++mt)
#pragma unroll
      for (int r = 0; r < 4; ++r) {
        int rowl = mt * 16 + kg * 4 + r;
        int rid = ridS[rowl];
        if (rid < 0) continue;
#pragma unroll
        for (int jt = 0; jt < 2; ++jt) {
          int j = wv * 32 + jt * 16 + r16;
          size_t xb = (size_t)rid * TH + j;
          float rg = sigm(bf2f(xproj[xb]) + vb[jt][0] + acc[mt][jt][r]);
          float zg = sigm(bf2f(xproj[xb + H]) + vb[jt][1] + acc[mt][2 + jt][r]);
          float ng = tanh_(bf2f(xproj[xb + 2 * H]) + vb[jt][2] + rg * (acc[mt][4 + jt][r] + vb[jt][3]));
          float hp = (s == 0) ? ldf(h0, wf32, (size_t)rid * H + j)
                              : out[(size_t)(rid - BA) * H + j];
          out[(size_t)rid * H + j] = (1.0f - zg) * ng + zg * hp;
        }
      }
  }
}

// ---- scan helpers (register-resident f16 weights; used by kscan + ktail) ----
#define LDW(VR, P, c) { uint4 q_ = *(const uint4*)((P) + (c) * 8); \
  VR[(c)*4+0] = q_.x; VR[(c)*4+1] = q_.y; VR[(c)*4+2] = q_.z; VR[(c)*4+3] = q_.w; }
#define LDWALL(VR, P) \
  LDW(VR,P,0) LDW(VR,P,1) LDW(VR,P,2) LDW(VR,P,3) LDW(VR,P,4) LDW(VR,P,5) LDW(VR,P,6) LDW(VR,P,7) \
  LDW(VR,P,8) LDW(VR,P,9) LDW(VR,P,10) LDW(VR,P,11) LDW(VR,P,12) LDW(VR,P,13) LDW(VR,P,14) LDW(VR,P,15)

#define BCH(x) __builtin_bit_cast(h2_t, (u32)(x))
#define DOTC(c) { uint4 hv_ = h4_[c]; \
  h2_t a0_ = __builtin_bit_cast(h2_t, hv_.x); \
  h2_t a1_ = __builtin_bit_cast(h2_t, hv_.y); \
  h2_t a2_ = __builtin_bit_cast(h2_t, hv_.z); \
  h2_t a3_ = __builtin_bit_cast(h2_t, hv_.w); \
  ar = F2(BCH(WR[4*(c)+0]), a0_, ar); az = F2(BCH(WZ[4*(c)+0]), a0_, az); an = F2(BCH(WN[4*(c)+0]), a0_, an); \
  ar = F2(BCH(WR[4*(c)+1]), a1_, ar); az = F2(BCH(WZ[4*(c)+1]), a1_, az); an = F2(BCH(WN[4*(c)+1]), a1_, an); \
  ar = F2(BCH(WR[4*(c)+2]), a2_, ar); az = F2(BCH(WZ[4*(c)+2]), a2_, az); an = F2(BCH(WN[4*(c)+2]), a2_, an); \
  ar = F2(BCH(WR[4*(c)+3]), a3_, ar); az = F2(BCH(WZ[4*(c)+3]), a3_, az); an = F2(BCH(WN[4*(c)+3]), a3_, an); }
#define DOT16 \
  DOTC(0) DOTC(1) DOTC(2) DOTC(3) DOTC(4) DOTC(5) DOTC(6) DOTC(7) \
  DOTC(8) DOTC(9) DOTC(10) DOTC(11) DOTC(12) DOTC(13) DOTC(14) DOTC(15)

// deep tail: rows with d >= NBUCK, processed serially per chain
__global__ __launch_bounds__(512, 2) void ktail(const u16* __restrict__ xproj,
                                                float* __restrict__ out,
                                                const u16* __restrict__ WhF,
                                                const unsigned char* __restrict__ dbuf,
                                                const void* __restrict__ bir, const void* __restrict__ biz,
                                                const void* __restrict__ bin_, const void* __restrict__ bhn,
                                                const int* __restrict__ flags) {
  int w = blockIdx.x;
  int tid = threadIdx.x;
  int j = tid >> 1;
  int half = tid & 1;
  bool wf32 = flags[2] != 0;
  __shared__ __align__(16) u16 hsb[256];
  __shared__ unsigned char dcol[1024];
  for (int t = tid; t < 1024; t += 512) dcol[t] = dbuf[(size_t)t * BA + w];
  const u16* pr = WhF + (size_t)j * H + half * 128;
  const u16* pz = WhF + (size_t)H * H + (size_t)j * H + half * 128;
  const u16* pn = WhF + (size_t)2 * H * H + (size_t)j * H + half * 128;
  v64u WR, WZ, WN;
  LDWALL(WR, pr)
  LDWALL(WZ, pz)
  LDWALL(WN, pn)
  float vbir = ldf(bir, wf32, j), vbiz = ldf(biz, wf32, j);
  float vbin = ldf(bin_, wf32, j), vbhn = ldf(bhn, wf32, j);
  __syncthreads();
  int prev_t = -99;
  float hreg = 0.0f;
#pragma unroll 1
  for (int t = 0; t < 1024; ++t) {
    int d = dcol[t];
    if (d < NBUCK || d == 255) continue;  // uniform across block
    if (prev_t != t - 1) {
      hreg = out[((size_t)(t - 1) * BA + w) * H + j];
      if (half == 0) { _Float16 hh = (_Float16)hreg; hsb[j] = __builtin_bit_cast(u16, hh); }
      __syncthreads();
    }
    const uint4* h4_ = (const uint4*)(&hsb[half * 128]);
    float ar = 0.0f, az = 0.0f, an = 0.0f;
    DOT16
    ar += __shfl_xor(ar, 1, 64);
    az += __shfl_xor(az, 1, 64);
    an += __shfl_xor(an, 1, 64);
    size_t xb = ((size_t)t * BA + w) * TH + j;
    float r = sigm(bf2f(xproj[xb]) + vbir + ar);
    float z = sigm(bf2f(xproj[xb + H]) + vbiz + az);
    float n = tanh_(bf2f(xproj[xb + 2 * H]) + vbin + r * (an + vbhn));
    float hnew = (1.0f - z) * n + z * hreg;
    if (half == 0) out[((size_t)t * BA + w) * H + j] = hnew;
    __syncthreads();
    if (half == 0) { _Float16 hh = (_Float16)hnew; hsb[j] = __builtin_bit_cast(u16, hh); }
    hreg = hnew;
    prev_t = t;
    __syncthreads();
  }
}

// ---- fallback serial scan (used only when workspace can't hold full xproj) ----
__global__ __launch_bounds__(512, 2) void kscan(
    const u16* __restrict__ xproj, const void* __restrict__ resets,
    const void* __restrict__ h0, float* __restrict__ carry,
    const u16* __restrict__ WhF,
    const void* __restrict__ bir, const void* __restrict__ biz, const void* __restrict__ bin_,
    const void* __restrict__ bhn, float* __restrict__ out, int t0, int Tc,
    const int* __restrict__ flags) {
  int w = blockIdx.x;
  int tid = threadIdx.x;
  int j = tid >> 1;
  int half = tid & 1;
  bool wf32 = flags[2] != 0;
  bool rbyte = flags[1] != 0;
  __shared__ __align__(16) u16 hsb[2][256];
  __shared__ int rstS[1024];

  for (int t = tid; t < Tc; t += 512)
    rstS[t] = ldrst(resets, rbyte, (size_t)(t0 + t) * BA + w);

  const u16* pr = WhF + (size_t)j * H + half * 128;
  const u16* pz = WhF + (size_t)H * H + (size_t)j * H + half * 128;
  const u16* pn = WhF + (size_t)2 * H * H + (size_t)j * H + half * 128;
  v64u WR, WZ, WN;
  LDWALL(WR, pr)
  LDWALL(WZ, pz)
  LDWALL(WN, pn)

  float vbir = ldf(bir, wf32, j), vbiz = ldf(biz, wf32, j);
  float vbin = ldf(bin_, wf32, j), vbhn = ldf(bhn, wf32, j);

  float hreg = (t0 == 0) ? ldf(h0, wf32, (size_t)w * H + j) : carry[(size_t)w * H + j];
  __syncthreads();
  if (rstS[0] != 0) hreg = 0.0f;
  if (half == 0) {
    _Float16 hh = (_Float16)hreg;
    hsb[0][j] = __builtin_bit_cast(u16, hh);
  }
  __syncthreads();

  size_t xb0 = (size_t)w * TH + j;
  u16 cxr = xproj[xb0], cxz = xproj[xb0 + H], cxn = xproj[xb0 + 2 * H];

#pragma unroll 1
  for (int tl = 0; tl < Tc; ++tl) {
    u16 nxr = 0, nxz = 0, nxn = 0;
    if (tl + 1 < Tc) {
      size_t nb = ((size_t)(tl + 1) * BA + w) * TH + j;
      nxr = xproj[nb]; nxz = xproj[nb + H]; nxn = xproj[nb + 2 * H];
    }
    const uint4* h4_ = (const uint4*)(&hsb[tl & 1][half * 128]);
    float ar = 0.0f, az = 0.0f, an = 0.0f;
    DOT16
    ar += __shfl_xor(ar, 1, 64);
    az += __shfl_xor(az, 1, 64);
    an += __shfl_xor(an, 1, 64);
    float r = sigm(bf2f(cxr) + vbir + ar);
    float z = sigm(bf2f(cxz) + vbiz + az);
    float n = tanh_(bf2f(cxn) + vbin + r * (an + vbhn));
    float hnew = (1.0f - z) * n + z * hreg;
    if (half == 0) out[((size_t)(t0 + tl) * BA + w) * H + j] = hnew;

    float hnext = hnew;
    if (tl + 1 < Tc && rstS[tl + 1] != 0) hnext = 0.0f;
    if (half == 0) {
      _Float16 hh = (_Float16)hnext;
      hsb[(tl & 1) ^ 1][j] = __builtin_bit_cast(u16, hh);
    }
    hreg = hnext;
    cxr = nxr; cxz = nxz; cxn = nxn;
    __syncthreads();
  }
  if (half == 0) carry[(size_t)w * H + j] = hreg;
}

extern "C" void kernel_launch(void* const* d_in, const int* in_sizes, int n_in,
                              void* d_out, int out_size, void* d_ws, size_t ws_size,
                              hipStream_t stream) {
  const void* ins = d_in[0];
  const void* resets = d_in[1];
  const void* h0 = d_in[2];
  const void* Wir = d_in[3];
  const void* Wiz = d_in[4];
  const void* Win = d_in[5];
  const void* bir = d_in[6];
  const void* biz = d_in[7];
  const void* bin_ = d_in[8];
  const void* Whr = d_in[9];
  const void* Whz = d_in[10];
  const void* Whn = d_in[11];
  const void* bhn = d_in[12];
  float* out = (float*)d_out;

  // ws: [flags][WT 768KB][carry 128KB][cnt 256B][dbuf 128KB][lists 2MB][WhB 384KB][insb 64MB?][xproj]
  const size_t off_wt = 256;
  const size_t wt_bytes = (size_t)6 * H * H * 2;
  const size_t off_carry = off_wt + wt_bytes;
  const size_t off_cnt = off_carry + (size_t)BA * H * 4;
  const size_t off_dbuf = off_cnt + 256;
  const size_t off_list = off_dbuf + NROWS;
  const size_t off_whb = off_list + (size_t)NBUCK * LCAP * 4;
  const size_t whb_bytes = (size_t)TH * H * 2;
  const size_t off_insb = off_whb + whb_bytes;
  const size_t insb_bytes = (size_t)1024 * BA * H * 2;
  const size_t chunk_bytes = (size_t)BA * TH * 2;

  int* flags = (int*)d_ws;
  u16* WT = (u16*)((char*)d_ws + off_wt);
  float* carry = (float*)((char*)d_ws + off_carry);
  int* cnt = (int*)((char*)d_ws + off_cnt);
  unsigned char* dbuf = (unsigned char*)((char*)d_ws + off_dbuf);
  u32* list = (u32*)((char*)d_ws + off_list);
  u16* WhB = (u16*)((char*)d_ws + off_whb);
  u16* insb = (u16*)((char*)d_ws + off_insb);

  int use_insb = (ws_size >= off_insb + insb_bytes + (size_t)1024 * chunk_bytes) ? 1 : 0;
  size_t off_xproj = use_insb ? (off_insb + insb_bytes) : off_insb;
  u16* xproj = (u16*)((char*)d_ws + off_xproj);

  kdetect<<<1, 256, 0, stream>>>((const u32*)ins, (const u32*)resets,
                                 (const u32*)Whr, (const u32*)Wir, flags, cnt);
  if (use_insb) kprep<<<16384, 256, 0, stream>>>(ins, insb, flags);
  ktrans<<<dim3(4, 4, 6), 256, 0, stream>>>(Wir, Wiz, Win, Whr, Whz, Whn, WT, flags);
  kswz<<<96, 256, 0, stream>>>(WT, WhB);

  const u16* WhT = WT + (size_t)3 * H * H;
  if (ws_size >= off_xproj + (size_t)1024 * chunk_bytes) {
    // segment-parallel path: full xproj, then process rows by reset-distance d
    kgemm<<<dim3(1024, 6), 256, 0, stream>>>(ins, insb, use_insb, 0, WT, xproj, flags);
    kdlists<<<512, 256, 0, stream>>>(resets, dbuf, cnt, list, flags);
    kelem<<<1024, 256, 0, stream>>>(xproj, resets, out, bir, biz, bin_, bhn, flags);
    for (int s = 0; s < NBUCK; ++s)
      kstep<<<1024, 512, 0, stream>>>(xproj, out, h0, WhB, cnt, list + (size_t)s * LCAP,
                                      bir, biz, bin_, bhn, flags, s);
    ktail<<<128, 512, 0, stream>>>(xproj, out, WhT, dbuf, bir, biz, bin_, bhn, flags);
  } else {
    // fallback: chunked serial scan
    int Tc = 1024;
    while (Tc > 1 && off_xproj + (size_t)Tc * chunk_bytes > ws_size) Tc >>= 1;
    int nchunks = 1024 / Tc;
    for (int c = 0; c < nchunks; ++c) {
      int t0 = c * Tc;
      kgemm<<<dim3(Tc, 6), 256, 0, stream>>>(ins, insb, use_insb, t0, WT, xproj, flags);
      kscan<<<128, 512, 0, stream>>>(xproj, resets, h0, carry, WhT,
                                     bir, biz, bin_, bhn, out, t0, Tc, flags);
    }
  }
}

// Round 3
// 892.850 us; speedup vs baseline: 1.4200x; 1.4200x over previous
//
#include <hip/hip_runtime.h>

#define BA 128
#define H 256
#define TH 768
#define NROWS (1024 * BA)
#define LCAP 65536
#define NBUCK 8
#define MT 32
#define AP 264

typedef _Float16 h2_t __attribute__((ext_vector_type(2)));
typedef _Float16 h8_t __attribute__((ext_vector_type(8)));
typedef short s8_t __attribute__((ext_vector_type(8)));
typedef float f4_t __attribute__((ext_vector_type(4)));
typedef unsigned short u16;
typedef u16 us4_t __attribute__((ext_vector_type(4)));
typedef unsigned int u32;
typedef u32 v64u __attribute__((ext_vector_type(64)));

__device__ __forceinline__ float bf2f(u16 u) {
  union { u32 i; float f; } c; c.i = ((u32)u) << 16; return c.f;
}
__device__ __forceinline__ u16 f2bf(float f) {
  union { float f; u32 i; } c; c.f = f;
  u32 r = c.i + 0x7FFFu + ((c.i >> 16) & 1u);
  return (u16)(r >> 16);
}
__device__ __forceinline__ float sigm(float x) {
  float e = __builtin_amdgcn_exp2f(-x * 1.442695040888963f);
  return __builtin_amdgcn_rcpf(1.0f + e);
}
__device__ __forceinline__ float tanh_(float x) {
  float e = __builtin_amdgcn_exp2f(x * 2.885390081777927f);
  return 1.0f - 2.0f * __builtin_amdgcn_rcpf(1.0f + e);
}
__device__ __forceinline__ float ldf(const void* p, bool f32, size_t idx) {
  return f32 ? ((const float*)p)[idx] : bf2f(((const u16*)p)[idx]);
}
__device__ __forceinline__ int ldrst(const void* p, bool isbyte, size_t idx) {
  return isbyte ? (int)((const unsigned char*)p)[idx] : ((const int*)p)[idx];
}
__device__ __forceinline__ float F2(h2_t a, h2_t b, float c) {
#if defined(__has_builtin) && __has_builtin(__builtin_amdgcn_fdot2)
  return __builtin_amdgcn_fdot2(a, b, c, false);
#else
  return c + (float)a[0] * (float)b[0] + (float)a[1] * (float)b[1];
#endif
}

// flags: [0]=ins_f32 [1]=resets_byte [2]=Wh_f32 [3]=Wi_f32
__global__ __launch_bounds__(256) void kdetect(const u32* __restrict__ insw,
                                               const u32* __restrict__ rstw,
                                               const u32* __restrict__ whrw,
                                               const u32* __restrict__ wirw,
                                               int* __restrict__ flags,
                                               int* __restrict__ cnt) {
  __shared__ int c0, c1, c2, c3;
  if (threadIdx.x == 0) { c0 = 0; c1 = 0; c2 = 0; c3 = 0; }
  if (threadIdx.x < NBUCK) cnt[threadIdx.x] = 0;
  __syncthreads();
  if (!(fabsf(bf2f((u16)(insw[threadIdx.x] & 0xFFFFu))) < 1e10f)) atomicAdd(&c0, 1);
  if (!(fabsf(bf2f((u16)(whrw[threadIdx.x] & 0xFFFFu))) < 1e10f)) atomicAdd(&c2, 1);
  if (!(fabsf(bf2f((u16)(wirw[threadIdx.x] & 0xFFFFu))) < 1e10f)) atomicAdd(&c3, 1);
  if (threadIdx.x < 128 && rstw[threadIdx.x] > 1u) atomicAdd(&c1, 1);
  __syncthreads();
  if (threadIdx.x == 0) {
    flags[0] = (c0 > 8) ? 1 : 0;
    flags[1] = (c1 > 0) ? 1 : 0;
    flags[2] = (c2 > 8) ? 1 : 0;
    flags[3] = (c3 > 8) ? 1 : 0;
  }
}

// convert ins -> bf16 (or pass-through)
__global__ __launch_bounds__(256) void kprep(const void* __restrict__ ins,
                                             u16* __restrict__ insb,
                                             const int* __restrict__ flags) {
  bool f32in = flags[0] != 0;
  size_t i0 = ((size_t)blockIdx.x * 256 + threadIdx.x) * 8;
  s8_t v;
  if (f32in) {
    f4_t x0 = *(const f4_t*)((const float*)ins + i0);
    f4_t x1 = *(const f4_t*)((const float*)ins + i0 + 4);
#pragma unroll
    for (int i = 0; i < 4; ++i) v[i] = (short)f2bf(x0[i]);
#pragma unroll
    for (int i = 0; i < 4; ++i) v[4 + i] = (short)f2bf(x1[i]);
  } else {
    v = *(const s8_t*)((const u16*)ins + i0);
  }
  *(s8_t*)(insb + i0) = v;
}

// WT[g][j][k] = W_g[k][j]; g=0..2 (Wi): bf16 for MFMA; g=3..5 (Wh): f16
__global__ __launch_bounds__(256) void ktrans(const void* __restrict__ W0, const void* __restrict__ W1,
                                              const void* __restrict__ W2, const void* __restrict__ W3,
                                              const void* __restrict__ W4, const void* __restrict__ W5,
                                              u16* __restrict__ WT, const int* __restrict__ flags) {
  __shared__ u16 tile[64][65];
  int g = blockIdx.z;
  bool f32in = ((g < 3) ? flags[3] : flags[2]) != 0;
  bool toF16 = (g >= 3);
  const void* srcs[6] = {W0, W1, W2, W3, W4, W5};
  const void* src = srcs[g];
  int k0 = blockIdx.x * 64, j0 = blockIdx.y * 64;
  int tid = threadIdx.x;
#pragma unroll
  for (int p = 0; p < 16; ++p) {
    int e = p * 256 + tid;
    int kr = e >> 6, jc = e & 63;
    size_t idx = (size_t)(k0 + kr) * H + j0 + jc;
    float v = f32in ? ((const float*)src)[idx] : bf2f(((const u16*)src)[idx]);
    u16 bits;
    if (toF16) {
      _Float16 h = (_Float16)v;
      bits = __builtin_bit_cast(u16, h);
    } else {
      bits = f2bf(v);
    }
    tile[kr][jc] = bits;
  }
  __syncthreads();
  u16* dst = WT + (size_t)g * H * H;
#pragma unroll
  for (int p = 0; p < 16; ++p) {
    int e = p * 256 + tid;
    int jr = e >> 6, kc = e & 63;
    dst[(size_t)(j0 + jr) * H + k0 + kc] = tile[kc][jr];
  }
}

// WhB: MFMA-fragment-ordered Wh^T (f16). fragment f=(kk*48+cg)*64+lane holds
// Wh_g^T[col=(cg&15)*16+(lane&15)][k=kk*32+(lane>>4)*8 .. +8], g=cg>>4.
__global__ __launch_bounds__(256) void kswz(const u16* __restrict__ WT, u16* __restrict__ WhB) {
  int f = blockIdx.x * 256 + threadIdx.x;  // 96 blocks * 256 = 24576 fragments
  if (f >= 8 * 48 * 64) return;
  int lane = f & 63;
  int cg = (f >> 6) % 48;
  int kk = (f >> 6) / 48;
  int g = cg >> 4;
  int col = ((cg & 15) << 4) + (lane & 15);
  int k0 = kk * 32 + ((lane >> 4) << 3);
  const u16* src = WT + (size_t)(3 + g) * H * H + (size_t)col * H + k0;
  *(s8_t*)(WhB + (size_t)f * 8) = *(const s8_t*)src;
}

// xproj[m, g*256+j] = ins[m,:] @ W_ig[:,j]  -> bf16
#define LDK 40
__global__ __launch_bounds__(256) void kgemm(const void* __restrict__ ins,
                                             const u16* __restrict__ insb, int use_insb,
                                             int t0, const u16* __restrict__ WT,
                                             u16* __restrict__ C,
                                             const int* __restrict__ flags) {
  __shared__ u16 As[128 * LDK];
  __shared__ u16 Bs[128 * LDK];
  bool f32in = flags[0] != 0;
  int tid = threadIdx.x;
  int row0 = blockIdx.x * 128;
  int col0 = blockIdx.y * 128;
  int gate = col0 >> 8;
  int j0 = col0 & 255;
  const u16* Bg = WT + (size_t)gate * H * H + (size_t)j0 * H;
  size_t abase = (size_t)t0 * BA * H;
  int lane = tid & 63;
  int wave = tid >> 6;
  int r16 = lane & 15;
  int kg = lane >> 4;
  f4_t acc[2][8];
#pragma unroll
  for (int rt = 0; rt < 2; ++rt)
#pragma unroll
    for (int ct = 0; ct < 8; ++ct) acc[rt][ct] = (f4_t)0.0f;

  for (int kk = 0; kk < 8; ++kk) {
    int k0 = kk * 32;
#pragma unroll
    for (int p = 0; p < 2; ++p) {
      int idx = p * 256 + tid;
      int m = idx >> 2;
      int kq = (idx & 3) * 8;
      size_t e = abase + (size_t)(row0 + m) * H + k0 + kq;
      s8_t v;
      if (use_insb) {
        v = *(const s8_t*)(insb + e);
      } else if (f32in) {
        f4_t x0 = *(const f4_t*)((const float*)ins + e);
        f4_t x1 = *(const f4_t*)((const float*)ins + e + 4);
#pragma unroll
        for (int i = 0; i < 4; ++i) v[i] = (short)f2bf(x0[i]);
#pragma unroll
        for (int i = 0; i < 4; ++i) v[4 + i] = (short)f2bf(x1[i]);
      } else {
        v = *(const s8_t*)((const u16*)ins + e);
      }
      *(s8_t*)(As + m * LDK + kq) = v;
    }
#pragma unroll
    for (int p = 0; p < 2; ++p) {
      int idx = p * 256 + tid;
      int n = idx >> 2;
      int kq = (idx & 3) * 8;
      s8_t v = *(const s8_t*)(Bg + (size_t)n * H + k0 + kq);
      *(s8_t*)(Bs + n * LDK + kq) = v;
    }
    __syncthreads();
    s8_t af[2], bf[8];
#pragma unroll
    for (int rt = 0; rt < 2; ++rt)
      af[rt] = *(const s8_t*)(As + (wave * 32 + rt * 16 + r16) * LDK + kg * 8);
#pragma unroll
    for (int ct = 0; ct < 8; ++ct)
      bf[ct] = *(const s8_t*)(Bs + (ct * 16 + r16) * LDK + kg * 8);
#pragma unroll
    for (int rt = 0; rt < 2; ++rt)
#pragma unroll
      for (int ct = 0; ct < 8; ++ct)
        acc[rt][ct] = __builtin_amdgcn_mfma_f32_16x16x32_bf16(af[rt], bf[ct], acc[rt][ct], 0, 0, 0);
    __syncthreads();
  }
#pragma unroll
  for (int rt = 0; rt < 2; ++rt)
#pragma unroll
    for (int ct = 0; ct < 8; ++ct)
#pragma unroll
      for (int r = 0; r < 4; ++r) {
        int grow = row0 + wave * 32 + rt * 16 + kg * 4 + r;
        int gcol = col0 + ct * 16 + r16;
        C[(size_t)grow * TH + gcol] = f2bf(acc[rt][ct][r]);
      }
}

// ---- segment-level machinery ----------------------------------------------
__global__ __launch_bounds__(256) void kdlists(const void* __restrict__ resets,
                                               unsigned char* __restrict__ dbuf,
                                               int* __restrict__ cnt,
                                               u32* __restrict__ list,
                                               const int* __restrict__ flags) {
  bool rbyte = flags[1] != 0;
  int id = blockIdx.x * 256 + threadIdx.x;  // grid 512 x 256 == NROWS
  int t = id >> 7, w = id & 127;
  int d;
  if (ldrst(resets, rbyte, id)) {
    d = 255;  // reset-row marker
  } else {
    int tr = t - 1;
    while (tr >= 0 && !ldrst(resets, rbyte, (size_t)tr * BA + w)) --tr;
    d = t - ((tr >= 0) ? tr : 0);
    if (d > 254) d = 254;
  }
  dbuf[id] = (unsigned char)d;
  int lane = threadIdx.x & 63;
#pragma unroll 1
  for (int s = 0; s < NBUCK; ++s) {
    unsigned long long m = __ballot(d == s);
    if (m) {
      int n = __popcll(m);
      int base = 0;
      if (lane == 0) base = atomicAdd(&cnt[s], n);
      base = __shfl(base, 0, 64);
      if (d == s) {
        int pos = base + (int)__popcll(m & ((1ull << lane) - 1ull));
        if (pos < LCAP) list[(size_t)s * LCAP + pos] = (u32)id;
      }
    }
  }
}

// all reset rows: h_prev = 0 -> pure elementwise from xproj
__global__ __launch_bounds__(256) void kelem(const u16* __restrict__ xproj,
                                             const void* __restrict__ resets,
                                             float* __restrict__ out,
                                             const void* __restrict__ bir, const void* __restrict__ biz,
                                             const void* __restrict__ bin_, const void* __restrict__ bhn,
                                             const int* __restrict__ flags) {
  bool rbyte = flags[1] != 0;
  bool wf32 = flags[2] != 0;
  int j = threadIdx.x;
  float vbir = ldf(bir, wf32, j), vbiz = ldf(biz, wf32, j);
  float vbin = ldf(bin_, wf32, j), vbhn = ldf(bhn, wf32, j);
  for (int i = blockIdx.x; i < NROWS; i += gridDim.x) {
    if (!ldrst(resets, rbyte, i)) continue;
    size_t xb = (size_t)i * TH + j;
    float r = sigm(bf2f(xproj[xb]) + vbir);
    float z = sigm(bf2f(xproj[xb + H]) + vbiz);
    float n = tanh_(bf2f(xproj[xb + 2 * H]) + vbin + r * vbhn);
    out[(size_t)i * H + j] = (1.0f - z) * n;
  }
}

// one d-level: gather h_prev rows into LDS (f16, full K), B direct from L2 in
// fragment order (WhB) -> no B staging, 2 barriers/tile, M=32 tiles.
// NOTE: no min-waves clause -- forcing occupancy caused VGPR=64 + scratch
// spills (WRITE_SIZE 404 MB, round 2). ~110 VGPR natural => 2 blocks/CU.
__global__ __launch_bounds__(512) void kstep(const u16* __restrict__ xproj,
                                             float* __restrict__ out,
                                             const void* __restrict__ h0,
                                             const u16* __restrict__ WhB,
                                             const int* __restrict__ cnt,
                                             const u32* __restrict__ list,
                                             const void* __restrict__ bir, const void* __restrict__ biz,
                                             const void* __restrict__ bin_, const void* __restrict__ bhn,
                                             const int* __restrict__ flags, int s) {
  int cs = cnt[s];
  if (cs <= 0) return;
  bool wf32 = flags[2] != 0;
  __shared__ __align__(16) u16 As[MT * AP];  // f16 h rows, full K=256
  __shared__ int ridS[MT];
  int tid = threadIdx.x;
  int lane = tid & 63;
  int wv = tid >> 6;
  int r16 = lane & 15;
  int kg = lane >> 4;
  int ntiles = (cs + MT - 1) / MT;
  float vb[2][4];
#pragma unroll
  for (int jt = 0; jt < 2; ++jt) {
    int j = wv * 32 + jt * 16 + r16;
    vb[jt][0] = ldf(bir, wf32, j);
    vb[jt][1] = ldf(biz, wf32, j);
    vb[jt][2] = ldf(bin_, wf32, j);
    vb[jt][3] = ldf(bhn, wf32, j);
  }
  const s8_t* WB = (const s8_t*)WhB;  // 16B fragments

  for (int tile = blockIdx.x; tile < ntiles; tile += gridDim.x) {
    __syncthreads();  // As/ridS reuse safe (prev epilogue done)
    {  // stage A: 16 threads/row, 16 f16 elements each
      int i = tid >> 4;
      int seg = tid & 15;
      int idx = tile * MT + i;
      int rid = (idx < cs) ? (int)list[idx] : -1;
      if (seg == 0) ridS[i] = rid;
      u16* dst = As + i * AP + seg * 16;
      if (rid >= 0) {
        if (s == 0) {
#pragma unroll
          for (int q = 0; q < 4; ++q) {
            us4_t hb;
#pragma unroll
            for (int e = 0; e < 4; ++e) {
              _Float16 hh = (_Float16)ldf(h0, wf32, (size_t)rid * H + seg * 16 + q * 4 + e);
              hb[e] = __builtin_bit_cast(u16, hh);
            }
            *(us4_t*)(dst + q * 4) = hb;
          }
        } else {
          const float* src = out + (size_t)(rid - BA) * H + seg * 16;
#pragma unroll
          for (int q = 0; q < 4; ++q) {
            f4_t v = *(const f4_t*)(src + q * 4);
            us4_t hb;
#pragma unroll
            for (int e = 0; e < 4; ++e) {
              _Float16 hh = (_Float16)v[e];
              hb[e] = __builtin_bit_cast(u16, hh);
            }
            *(us4_t*)(dst + q * 4) = hb;
          }
        }
      } else {
        us4_t hz; hz[0] = 0; hz[1] = 0; hz[2] = 0; hz[3] = 0;
#pragma unroll
        for (int q = 0; q < 4; ++q) *(us4_t*)(dst + q * 4) = hz;
      }
    }
    __syncthreads();

    f4_t acc[2][6];
#pragma unroll
    for (int a = 0; a < 2; ++a)
#pragma unroll
      for (int b = 0; b < 6; ++b) acc[a][b] = (f4_t)0.0f;

#pragma unroll 2
    for (int kk = 0; kk < 8; ++kk) {
      h8_t af[2];
#pragma unroll
      for (int mt = 0; mt < 2; ++mt)
        af[mt] = __builtin_bit_cast(h8_t,
            *(const s8_t*)(As + (mt * 16 + r16) * AP + kk * 32 + kg * 8));
      s8_t bfr[6];
#pragma unroll
      for (int g = 0; g < 3; ++g)
#pragma unroll
        for (int jt = 0; jt < 2; ++jt) {
          int cg = g * 16 + wv * 2 + jt;
          bfr[g * 2 + jt] = WB[(size_t)((kk * 48 + cg) * 64 + lane)];
        }
#pragma unroll
      for (int c = 0; c < 6; ++c)
#pragma unroll
        for (int mt = 0; mt < 2; ++mt)
          acc[mt][c] = __builtin_amdgcn_mfma_f32_16x16x32_f16(
              af[mt], __builtin_bit_cast(h8_t, bfr[c]), acc[mt][c], 0, 0, 0);
    }

    // epilogue: row = mt*16 + kg*4 + r, col = wv*32 + jt*16 + r16
#pragma unroll
    for (int mt = 0; mt < 2; ++mt)
#pragma unroll
      for (int r = 0; r < 4; ++r) {
        int rowl = mt * 16 + kg * 4 + r;
        int rid = ridS[rowl];
        if (rid < 0) continue;
#pragma unroll
        for (int jt = 0; jt < 2; ++jt) {
          int j = wv * 32 + jt * 16 + r16;
          size_t xb = (size_t)rid * TH + j;
          float rg = sigm(bf2f(xproj[xb]) + vb[jt][0] + acc[mt][jt][r]);
          float zg = sigm(bf2f(xproj[xb + H]) + vb[jt][1] + acc[mt][2 + jt][r]);
          float ng = tanh_(bf2f(xproj[xb + 2 * H]) + vb[jt][2] + rg * (acc[mt][4 + jt][r] + vb[jt][3]));
          float hp = (s == 0) ? ldf(h0, wf32, (size_t)rid * H + j)
                              : out[(size_t)(rid - BA) * H + j];
          out[(size_t)rid * H + j] = (1.0f - zg) * ng + zg * hp;
        }
      }
  }
}

// ---- scan helpers (register-resident f16 weights; used by kscan + ktail) ----
#define LDW(VR, P, c) { uint4 q_ = *(const uint4*)((P) + (c) * 8); \
  VR[(c)*4+0] = q_.x; VR[(c)*4+1] = q_.y; VR[(c)*4+2] = q_.z; VR[(c)*4+3] = q_.w; }
#define LDWALL(VR, P) \
  LDW(VR,P,0) LDW(VR,P,1) LDW(VR,P,2) LDW(VR,P,3) LDW(VR,P,4) LDW(VR,P,5) LDW(VR,P,6) LDW(VR,P,7) \
  LDW(VR,P,8) LDW(VR,P,9) LDW(VR,P,10) LDW(VR,P,11) LDW(VR,P,12) LDW(VR,P,13) LDW(VR,P,14) LDW(VR,P,15)

#define BCH(x) __builtin_bit_cast(h2_t, (u32)(x))
#define DOTC(c) { uint4 hv_ = h4_[c]; \
  h2_t a0_ = __builtin_bit_cast(h2_t, hv_.x); \
  h2_t a1_ = __builtin_bit_cast(h2_t, hv_.y); \
  h2_t a2_ = __builtin_bit_cast(h2_t, hv_.z); \
  h2_t a3_ = __builtin_bit_cast(h2_t, hv_.w); \
  ar = F2(BCH(WR[4*(c)+0]), a0_, ar); az = F2(BCH(WZ[4*(c)+0]), a0_, az); an = F2(BCH(WN[4*(c)+0]), a0_, an); \
  ar = F2(BCH(WR[4*(c)+1]), a1_, ar); az = F2(BCH(WZ[4*(c)+1]), a1_, az); an = F2(BCH(WN[4*(c)+1]), a1_, an); \
  ar = F2(BCH(WR[4*(c)+2]), a2_, ar); az = F2(BCH(WZ[4*(c)+2]), a2_, az); an = F2(BCH(WN[4*(c)+2]), a2_, an); \
  ar = F2(BCH(WR[4*(c)+3]), a3_, ar); az = F2(BCH(WZ[4*(c)+3]), a3_, az); an = F2(BCH(WN[4*(c)+3]), a3_, an); }
#define DOT16 \
  DOTC(0) DOTC(1) DOTC(2) DOTC(3) DOTC(4) DOTC(5) DOTC(6) DOTC(7) \
  DOTC(8) DOTC(9) DOTC(10) DOTC(11) DOTC(12) DOTC(13) DOTC(14) DOTC(15)

// deep tail: rows with d >= NBUCK, processed serially per chain
__global__ __launch_bounds__(512, 2) void ktail(const u16* __restrict__ xproj,
                                                float* __restrict__ out,
                                                const u16* __restrict__ WhF,
                                                const unsigned char* __restrict__ dbuf,
                                                const void* __restrict__ bir, const void* __restrict__ biz,
                                                const void* __restrict__ bin_, const void* __restrict__ bhn,
                                                const int* __restrict__ flags) {
  int w = blockIdx.x;
  int tid = threadIdx.x;
  int j = tid >> 1;
  int half = tid & 1;
  bool wf32 = flags[2] != 0;
  __shared__ __align__(16) u16 hsb[256];
  __shared__ unsigned char dcol[1024];
  for (int t = tid; t < 1024; t += 512) dcol[t] = dbuf[(size_t)t * BA + w];
  const u16* pr = WhF + (size_t)j * H + half * 128;
  const u16* pz = WhF + (size_t)H * H + (size_t)j * H + half * 128;
  const u16* pn = WhF + (size_t)2 * H * H + (size_t)j * H + half * 128;
  v64u WR, WZ, WN;
  LDWALL(WR, pr)
  LDWALL(WZ, pz)
  LDWALL(WN, pn)
  float vbir = ldf(bir, wf32, j), vbiz = ldf(biz, wf32, j);
  float vbin = ldf(bin_, wf32, j), vbhn = ldf(bhn, wf32, j);
  __syncthreads();
  int prev_t = -99;
  float hreg = 0.0f;
#pragma unroll 1
  for (int t = 0; t < 1024; ++t) {
    int d = dcol[t];
    if (d < NBUCK || d == 255) continue;  // uniform across block
    if (prev_t != t - 1) {
      hreg = out[((size_t)(t - 1) * BA + w) * H + j];
      if (half == 0) { _Float16 hh = (_Float16)hreg; hsb[j] = __builtin_bit_cast(u16, hh); }
      __syncthreads();
    }
    const uint4* h4_ = (const uint4*)(&hsb[half * 128]);
    float ar = 0.0f, az = 0.0f, an = 0.0f;
    DOT16
    ar += __shfl_xor(ar, 1, 64);
    az += __shfl_xor(az, 1, 64);
    an += __shfl_xor(an, 1, 64);
    size_t xb = ((size_t)t * BA + w) * TH + j;
    float r = sigm(bf2f(xproj[xb]) + vbir + ar);
    float z = sigm(bf2f(xproj[xb + H]) + vbiz + az);
    float n = tanh_(bf2f(xproj[xb + 2 * H]) + vbin + r * (an + vbhn));
    float hnew = (1.0f - z) * n + z * hreg;
    if (half == 0) out[((size_t)t * BA + w) * H + j] = hnew;
    __syncthreads();
    if (half == 0) { _Float16 hh = (_Float16)hnew; hsb[j] = __builtin_bit_cast(u16, hh); }
    hreg = hnew;
    prev_t = t;
    __syncthreads();
  }
}

// ---- fallback serial scan (used only when workspace can't hold full xproj) ----
__global__ __launch_bounds__(512, 2) void kscan(
    const u16* __restrict__ xproj, const void* __restrict__ resets,
    const void* __restrict__ h0, float* __restrict__ carry,
    const u16* __restrict__ WhF,
    const void* __restrict__ bir, const void* __restrict__ biz, const void* __restrict__ bin_,
    const void* __restrict__ bhn, float* __restrict__ out, int t0, int Tc,
    const int* __restrict__ flags) {
  int w = blockIdx.x;
  int tid = threadIdx.x;
  int j = tid >> 1;
  int half = tid & 1;
  bool wf32 = flags[2] != 0;
  bool rbyte = flags[1] != 0;
  __shared__ __align__(16) u16 hsb[2][256];
  __shared__ int rstS[1024];

  for (int t = tid; t < Tc; t += 512)
    rstS[t] = ldrst(resets, rbyte, (size_t)(t0 + t) * BA + w);

  const u16* pr = WhF + (size_t)j * H + half * 128;
  const u16* pz = WhF + (size_t)H * H + (size_t)j * H + half * 128;
  const u16* pn = WhF + (size_t)2 * H * H + (size_t)j * H + half * 128;
  v64u WR, WZ, WN;
  LDWALL(WR, pr)
  LDWALL(WZ, pz)
  LDWALL(WN, pn)

  float vbir = ldf(bir, wf32, j), vbiz = ldf(biz, wf32, j);
  float vbin = ldf(bin_, wf32, j), vbhn = ldf(bhn, wf32, j);

  float hreg = (t0 == 0) ? ldf(h0, wf32, (size_t)w * H + j) : carry[(size_t)w * H + j];
  __syncthreads();
  if (rstS[0] != 0) hreg = 0.0f;
  if (half == 0) {
    _Float16 hh = (_Float16)hreg;
    hsb[0][j] = __builtin_bit_cast(u16, hh);
  }
  __syncthreads();

  size_t xb0 = (size_t)w * TH + j;
  u16 cxr = xproj[xb0], cxz = xproj[xb0 + H], cxn = xproj[xb0 + 2 * H];

#pragma unroll 1
  for (int tl = 0; tl < Tc; ++tl) {
    u16 nxr = 0, nxz = 0, nxn = 0;
    if (tl + 1 < Tc) {
      size_t nb = ((size_t)(tl + 1) * BA + w) * TH + j;
      nxr = xproj[nb]; nxz = xproj[nb + H]; nxn = xproj[nb + 2 * H];
    }
    const uint4* h4_ = (const uint4*)(&hsb[tl & 1][half * 128]);
    float ar = 0.0f, az = 0.0f, an = 0.0f;
    DOT16
    ar += __shfl_xor(ar, 1, 64);
    az += __shfl_xor(az, 1, 64);
    an += __shfl_xor(an, 1, 64);
    float r = sigm(bf2f(cxr) + vbir + ar);
    float z = sigm(bf2f(cxz) + vbiz + az);
    float n = tanh_(bf2f(cxn) + vbin + r * (an + vbhn));
    float hnew = (1.0f - z) * n + z * hreg;
    if (half == 0) out[((size_t)(t0 + tl) * BA + w) * H + j] = hnew;

    float hnext = hnew;
    if (tl + 1 < Tc && rstS[tl + 1] != 0) hnext = 0.0f;
    if (half == 0) {
      _Float16 hh = (_Float16)hnext;
      hsb[(tl & 1) ^ 1][j] = __builtin_bit_cast(u16, hh);
    }
    hreg = hnext;
    cxr = nxr; cxz = nxz; cxn = nxn;
    __syncthreads();
  }
  if (half == 0) carry[(size_t)w * H + j] = hreg;
}

extern "C" void kernel_launch(void* const* d_in, const int* in_sizes, int n_in,
                              void* d_out, int out_size, void* d_ws, size_t ws_size,
                              hipStream_t stream) {
  const void* ins = d_in[0];
  const void* resets = d_in[1];
  const void* h0 = d_in[2];
  const void* Wir = d_in[3];
  const void* Wiz = d_in[4];
  const void* Win = d_in[5];
  const void* bir = d_in[6];
  const void* biz = d_in[7];
  const void* bin_ = d_in[8];
  const void* Whr = d_in[9];
  const void* Whz = d_in[10];
  const void* Whn = d_in[11];
  const void* bhn = d_in[12];
  float* out = (float*)d_out;

  // ws: [flags][WT 768KB][carry 128KB][cnt 256B][dbuf 128KB][lists 2MB][WhB 384KB][insb 64MB?][xproj]
  const size_t off_wt = 256;
  const size_t wt_bytes = (size_t)6 * H * H * 2;
  const size_t off_carry = off_wt + wt_bytes;
  const size_t off_cnt = off_carry + (size_t)BA * H * 4;
  const size_t off_dbuf = off_cnt + 256;
  const size_t off_list = off_dbuf + NROWS;
  const size_t off_whb = off_list + (size_t)NBUCK * LCAP * 4;
  const size_t whb_bytes = (size_t)TH * H * 2;
  const size_t off_insb = off_whb + whb_bytes;
  const size_t insb_bytes = (size_t)1024 * BA * H * 2;
  const size_t chunk_bytes = (size_t)BA * TH * 2;

  int* flags = (int*)d_ws;
  u16* WT = (u16*)((char*)d_ws + off_wt);
  float* carry = (float*)((char*)d_ws + off_carry);
  int* cnt = (int*)((char*)d_ws + off_cnt);
  unsigned char* dbuf = (unsigned char*)((char*)d_ws + off_dbuf);
  u32* list = (u32*)((char*)d_ws + off_list);
  u16* WhB = (u16*)((char*)d_ws + off_whb);
  u16* insb = (u16*)((char*)d_ws + off_insb);

  int use_insb = (ws_size >= off_insb + insb_bytes + (size_t)1024 * chunk_bytes) ? 1 : 0;
  size_t off_xproj = use_insb ? (off_insb + insb_bytes) : off_insb;
  u16* xproj = (u16*)((char*)d_ws + off_xproj);

  kdetect<<<1, 256, 0, stream>>>((const u32*)ins, (const u32*)resets,
                                 (const u32*)Whr, (const u32*)Wir, flags, cnt);
  if (use_insb) kprep<<<16384, 256, 0, stream>>>(ins, insb, flags);
  ktrans<<<dim3(4, 4, 6), 256, 0, stream>>>(Wir, Wiz, Win, Whr, Whz, Whn, WT, flags);
  kswz<<<96, 256, 0, stream>>>(WT, WhB);

  const u16* WhT = WT + (size_t)3 * H * H;
  if (ws_size >= off_xproj + (size_t)1024 * chunk_bytes) {
    // segment-parallel path: full xproj, then process rows by reset-distance d
    kgemm<<<dim3(1024, 6), 256, 0, stream>>>(ins, insb, use_insb, 0, WT, xproj, flags);
    kdlists<<<512, 256, 0, stream>>>(resets, dbuf, cnt, list, flags);
    kelem<<<1024, 256, 0, stream>>>(xproj, resets, out, bir, biz, bin_, bhn, flags);
    for (int s = 0; s < NBUCK; ++s)
      kstep<<<1024, 512, 0, stream>>>(xproj, out, h0, WhB, cnt, list + (size_t)s * LCAP,
                                      bir, biz, bin_, bhn, flags, s);
    ktail<<<128, 512, 0, stream>>>(xproj, out, WhT, dbuf, bir, biz, bin_, bhn, flags);
  } else {
    // fallback: chunked serial scan
    int Tc = 1024;
    while (Tc > 1 && off_xproj + (size_t)Tc * chunk_bytes > ws_size) Tc >>= 1;
    int nchunks = 1024 / Tc;
    for (int c = 0; c < nchunks; ++c) {
      int t0 = c * Tc;
      kgemm<<<dim3(Tc, 6), 256, 0, stream>>>(ins, insb, use_insb, t0, WT, xproj, flags);
      kscan<<<128, 512, 0, stream>>>(xproj, resets, h0, carry, WhT,
                                     bir, biz, bin_, bhn, out, t0, Tc, flags);
    }
  }
}

// Round 4
// 779.965 us; speedup vs baseline: 1.6255x; 1.1447x over previous
//
#include <hip/hip_runtime.h>

#define BA 128
#define H 256
#define TH 768
#define NROWS (1024 * BA)
#define LCAP 65536
#define NBUCK 8
#define MT 32
#define AP 264

typedef _Float16 h2_t __attribute__((ext_vector_type(2)));
typedef _Float16 h8_t __attribute__((ext_vector_type(8)));
typedef short s8_t __attribute__((ext_vector_type(8)));
typedef float f4_t __attribute__((ext_vector_type(4)));
typedef unsigned short u16;
typedef u16 us4_t __attribute__((ext_vector_type(4)));
typedef unsigned int u32;
typedef u32 v64u __attribute__((ext_vector_type(64)));

__device__ __forceinline__ float bf2f(u16 u) {
  union { u32 i; float f; } c; c.i = ((u32)u) << 16; return c.f;
}
__device__ __forceinline__ u16 f2bf(float f) {
  union { float f; u32 i; } c; c.f = f;
  u32 r = c.i + 0x7FFFu + ((c.i >> 16) & 1u);
  return (u16)(r >> 16);
}
__device__ __forceinline__ float sigm(float x) {
  float e = __builtin_amdgcn_exp2f(-x * 1.442695040888963f);
  return __builtin_amdgcn_rcpf(1.0f + e);
}
__device__ __forceinline__ float tanh_(float x) {
  float e = __builtin_amdgcn_exp2f(x * 2.885390081777927f);
  return 1.0f - 2.0f * __builtin_amdgcn_rcpf(1.0f + e);
}
__device__ __forceinline__ float ldf(const void* p, bool f32, size_t idx) {
  return f32 ? ((const float*)p)[idx] : bf2f(((const u16*)p)[idx]);
}
__device__ __forceinline__ int ldrst(const void* p, bool isbyte, size_t idx) {
  return isbyte ? (int)((const unsigned char*)p)[idx] : ((const int*)p)[idx];
}
__device__ __forceinline__ float F2(h2_t a, h2_t b, float c) {
#if defined(__has_builtin) && __has_builtin(__builtin_amdgcn_fdot2)
  return __builtin_amdgcn_fdot2(a, b, c, false);
#else
  return c + (float)a[0] * (float)b[0] + (float)a[1] * (float)b[1];
#endif
}

// flags: [0]=ins_f32 [1]=resets_byte [2]=Wh_f32 [3]=Wi_f32
__global__ __launch_bounds__(256) void kdetect(const u32* __restrict__ insw,
                                               const u32* __restrict__ rstw,
                                               const u32* __restrict__ whrw,
                                               const u32* __restrict__ wirw,
                                               int* __restrict__ flags,
                                               int* __restrict__ cnt) {
  __shared__ int c0, c1, c2, c3;
  if (threadIdx.x == 0) { c0 = 0; c1 = 0; c2 = 0; c3 = 0; }
  if (threadIdx.x < NBUCK) cnt[threadIdx.x] = 0;
  __syncthreads();
  if (!(fabsf(bf2f((u16)(insw[threadIdx.x] & 0xFFFFu))) < 1e10f)) atomicAdd(&c0, 1);
  if (!(fabsf(bf2f((u16)(whrw[threadIdx.x] & 0xFFFFu))) < 1e10f)) atomicAdd(&c2, 1);
  if (!(fabsf(bf2f((u16)(wirw[threadIdx.x] & 0xFFFFu))) < 1e10f)) atomicAdd(&c3, 1);
  if (threadIdx.x < 128 && rstw[threadIdx.x] > 1u) atomicAdd(&c1, 1);
  __syncthreads();
  if (threadIdx.x == 0) {
    flags[0] = (c0 > 8) ? 1 : 0;
    flags[1] = (c1 > 0) ? 1 : 0;
    flags[2] = (c2 > 8) ? 1 : 0;
    flags[3] = (c3 > 8) ? 1 : 0;
  }
}

// convert ins -> bf16 (or pass-through)
__global__ __launch_bounds__(256) void kprep(const void* __restrict__ ins,
                                             u16* __restrict__ insb,
                                             const int* __restrict__ flags) {
  bool f32in = flags[0] != 0;
  size_t i0 = ((size_t)blockIdx.x * 256 + threadIdx.x) * 8;
  s8_t v;
  if (f32in) {
    f4_t x0 = *(const f4_t*)((const float*)ins + i0);
    f4_t x1 = *(const f4_t*)((const float*)ins + i0 + 4);
#pragma unroll
    for (int i = 0; i < 4; ++i) v[i] = (short)f2bf(x0[i]);
#pragma unroll
    for (int i = 0; i < 4; ++i) v[4 + i] = (short)f2bf(x1[i]);
  } else {
    v = *(const s8_t*)((const u16*)ins + i0);
  }
  *(s8_t*)(insb + i0) = v;
}

// WT[g][j][k] = W_g[k][j]; g=0..2 (Wi): bf16 for MFMA; g=3..5 (Wh): f16
__global__ __launch_bounds__(256) void ktrans(const void* __restrict__ W0, const void* __restrict__ W1,
                                              const void* __restrict__ W2, const void* __restrict__ W3,
                                              const void* __restrict__ W4, const void* __restrict__ W5,
                                              u16* __restrict__ WT, const int* __restrict__ flags) {
  __shared__ u16 tile[64][65];
  int g = blockIdx.z;
  bool f32in = ((g < 3) ? flags[3] : flags[2]) != 0;
  bool toF16 = (g >= 3);
  const void* srcs[6] = {W0, W1, W2, W3, W4, W5};
  const void* src = srcs[g];
  int k0 = blockIdx.x * 64, j0 = blockIdx.y * 64;
  int tid = threadIdx.x;
#pragma unroll
  for (int p = 0; p < 16; ++p) {
    int e = p * 256 + tid;
    int kr = e >> 6, jc = e & 63;
    size_t idx = (size_t)(k0 + kr) * H + j0 + jc;
    float v = f32in ? ((const float*)src)[idx] : bf2f(((const u16*)src)[idx]);
    u16 bits;
    if (toF16) {
      _Float16 h = (_Float16)v;
      bits = __builtin_bit_cast(u16, h);
    } else {
      bits = f2bf(v);
    }
    tile[kr][jc] = bits;
  }
  __syncthreads();
  u16* dst = WT + (size_t)g * H * H;
#pragma unroll
  for (int p = 0; p < 16; ++p) {
    int e = p * 256 + tid;
    int jr = e >> 6, kc = e & 63;
    dst[(size_t)(j0 + jr) * H + k0 + kc] = tile[kc][jr];
  }
}

// WhB: MFMA-fragment-ordered Wh^T (f16). fragment f=(kk*48+cg)*64+lane holds
// Wh_g^T[col=(cg&15)*16+(lane&15)][k=kk*32+(lane>>4)*8 .. +8], g=cg>>4.
__global__ __launch_bounds__(256) void kswz(const u16* __restrict__ WT, u16* __restrict__ WhB) {
  int f = blockIdx.x * 256 + threadIdx.x;  // 96 blocks * 256 = 24576 fragments
  if (f >= 8 * 48 * 64) return;
  int lane = f & 63;
  int cg = (f >> 6) % 48;
  int kk = (f >> 6) / 48;
  int g = cg >> 4;
  int col = ((cg & 15) << 4) + (lane & 15);
  int k0 = kk * 32 + ((lane >> 4) << 3);
  const u16* src = WT + (size_t)(3 + g) * H * H + (size_t)col * H + k0;
  *(s8_t*)(WhB + (size_t)f * 8) = *(const s8_t*)src;
}

// xproj[m, g*256+j] = ins[m,:] @ W_ig[:,j]  -> bf16
#define LDK 40
__global__ __launch_bounds__(256) void kgemm(const void* __restrict__ ins,
                                             const u16* __restrict__ insb, int use_insb,
                                             int t0, const u16* __restrict__ WT,
                                             u16* __restrict__ C,
                                             const int* __restrict__ flags) {
  __shared__ u16 As[128 * LDK];
  __shared__ u16 Bs[128 * LDK];
  bool f32in = flags[0] != 0;
  int tid = threadIdx.x;
  int row0 = blockIdx.x * 128;
  int col0 = blockIdx.y * 128;
  int gate = col0 >> 8;
  int j0 = col0 & 255;
  const u16* Bg = WT + (size_t)gate * H * H + (size_t)j0 * H;
  size_t abase = (size_t)t0 * BA * H;
  int lane = tid & 63;
  int wave = tid >> 6;
  int r16 = lane & 15;
  int kg = lane >> 4;
  f4_t acc[2][8];
#pragma unroll
  for (int rt = 0; rt < 2; ++rt)
#pragma unroll
    for (int ct = 0; ct < 8; ++ct) acc[rt][ct] = (f4_t)0.0f;

  for (int kk = 0; kk < 8; ++kk) {
    int k0 = kk * 32;
#pragma unroll
    for (int p = 0; p < 2; ++p) {
      int idx = p * 256 + tid;
      int m = idx >> 2;
      int kq = (idx & 3) * 8;
      size_t e = abase + (size_t)(row0 + m) * H + k0 + kq;
      s8_t v;
      if (use_insb) {
        v = *(const s8_t*)(insb + e);
      } else if (f32in) {
        f4_t x0 = *(const f4_t*)((const float*)ins + e);
        f4_t x1 = *(const f4_t*)((const float*)ins + e + 4);
#pragma unroll
        for (int i = 0; i < 4; ++i) v[i] = (short)f2bf(x0[i]);
#pragma unroll
        for (int i = 0; i < 4; ++i) v[4 + i] = (short)f2bf(x1[i]);
      } else {
        v = *(const s8_t*)((const u16*)ins + e);
      }
      *(s8_t*)(As + m * LDK + kq) = v;
    }
#pragma unroll
    for (int p = 0; p < 2; ++p) {
      int idx = p * 256 + tid;
      int n = idx >> 2;
      int kq = (idx & 3) * 8;
      s8_t v = *(const s8_t*)(Bg + (size_t)n * H + k0 + kq);
      *(s8_t*)(Bs + n * LDK + kq) = v;
    }
    __syncthreads();
    s8_t af[2], bf[8];
#pragma unroll
    for (int rt = 0; rt < 2; ++rt)
      af[rt] = *(const s8_t*)(As + (wave * 32 + rt * 16 + r16) * LDK + kg * 8);
#pragma unroll
    for (int ct = 0; ct < 8; ++ct)
      bf[ct] = *(const s8_t*)(Bs + (ct * 16 + r16) * LDK + kg * 8);
#pragma unroll
    for (int rt = 0; rt < 2; ++rt)
#pragma unroll
      for (int ct = 0; ct < 8; ++ct)
        acc[rt][ct] = __builtin_amdgcn_mfma_f32_16x16x32_bf16(af[rt], bf[ct], acc[rt][ct], 0, 0, 0);
    __syncthreads();
  }
#pragma unroll
  for (int rt = 0; rt < 2; ++rt)
#pragma unroll
    for (int ct = 0; ct < 8; ++ct)
#pragma unroll
      for (int r = 0; r < 4; ++r) {
        int grow = row0 + wave * 32 + rt * 16 + kg * 4 + r;
        int gcol = col0 + ct * 16 + r16;
        C[(size_t)grow * TH + gcol] = f2bf(acc[rt][ct][r]);
      }
}

// ---- segment-level machinery ----------------------------------------------
// One block per chain w. Reset column in LDS; walk-back in LDS; one global
// atomicAdd per (block, bucket) -- was 16k contended global atomics (124 us).
// dbuf layout: [w][t] (coalesced both here and in ktail).
__global__ __launch_bounds__(256) void kdlists(const void* __restrict__ resets,
                                               unsigned char* __restrict__ dbuf,
                                               int* __restrict__ cnt,
                                               u32* __restrict__ list,
                                               const int* __restrict__ flags) {
  bool rbyte = flags[1] != 0;
  int w = blockIdx.x;  // 128 blocks
  int tid = threadIdx.x;
  __shared__ unsigned char rst[1024];
  __shared__ unsigned char dS[1024];
  __shared__ int lcnt[NBUCK], lbase[NBUCK], lpos[NBUCK];
  if (tid < NBUCK) { lcnt[tid] = 0; lpos[tid] = 0; }
  for (int t = tid; t < 1024; t += 256)
    rst[t] = (unsigned char)(ldrst(resets, rbyte, (size_t)t * BA + w) != 0);
  __syncthreads();
#pragma unroll
  for (int p = 0; p < 4; ++p) {
    int t = p * 256 + tid;
    int d;
    if (rst[t]) {
      d = 255;
    } else {
      int tr = t - 1;
      while (tr >= 0 && !rst[tr]) --tr;
      d = t - ((tr >= 0) ? tr : 0);
      if (d > 254) d = 254;
    }
    dS[t] = (unsigned char)d;
    if (d < NBUCK) atomicAdd(&lcnt[d], 1);
  }
  __syncthreads();
  if (tid < NBUCK) lbase[tid] = atomicAdd(&cnt[tid], lcnt[tid]);
  // coalesced dbuf write while the base atomics land
  for (int t = tid; t < 1024; t += 256) dbuf[(size_t)w * 1024 + t] = dS[t];
  __syncthreads();
#pragma unroll
  for (int p = 0; p < 4; ++p) {
    int t = p * 256 + tid;
    int d = dS[t];
    if (d < NBUCK) {
      int pos = lbase[d] + atomicAdd(&lpos[d], 1);
      if (pos < LCAP) list[(size_t)d * LCAP + pos] = (u32)(t * BA + w);
    }
  }
}

// all reset rows: h_prev = 0 -> pure elementwise from xproj
__global__ __launch_bounds__(256) void kelem(const u16* __restrict__ xproj,
                                             const void* __restrict__ resets,
                                             float* __restrict__ out,
                                             const void* __restrict__ bir, const void* __restrict__ biz,
                                             const void* __restrict__ bin_, const void* __restrict__ bhn,
                                             const int* __restrict__ flags) {
  bool rbyte = flags[1] != 0;
  bool wf32 = flags[2] != 0;
  int j = threadIdx.x;
  float vbir = ldf(bir, wf32, j), vbiz = ldf(biz, wf32, j);
  float vbin = ldf(bin_, wf32, j), vbhn = ldf(bhn, wf32, j);
  for (int i = blockIdx.x; i < NROWS; i += gridDim.x) {
    if (!ldrst(resets, rbyte, i)) continue;
    size_t xb = (size_t)i * TH + j;
    float r = sigm(bf2f(xproj[xb]) + vbir);
    float z = sigm(bf2f(xproj[xb + H]) + vbiz);
    float n = tanh_(bf2f(xproj[xb + 2 * H]) + vbin + r * vbhn);
    out[(size_t)i * H + j] = (1.0f - z) * n;
  }
}

// one d-level: gather h_prev rows into LDS (f16, full K), B direct from L2 in
// fragment order (WhB) -> no B staging, 2 barriers/tile, M=32 tiles.
// NOTE: no min-waves clause -- forcing occupancy caused VGPR=64 + scratch
// spills (WRITE_SIZE 404 MB, round 2). ~110 VGPR natural => 2 blocks/CU.
__global__ __launch_bounds__(512) void kstep(const u16* __restrict__ xproj,
                                             float* __restrict__ out,
                                             const void* __restrict__ h0,
                                             const u16* __restrict__ WhB,
                                             const int* __restrict__ cnt,
                                             const u32* __restrict__ list,
                                             const void* __restrict__ bir, const void* __restrict__ biz,
                                             const void* __restrict__ bin_, const void* __restrict__ bhn,
                                             const int* __restrict__ flags, int s) {
  int cs = cnt[s];
  if (cs <= 0) return;
  bool wf32 = flags[2] != 0;
  __shared__ __align__(16) u16 As[MT * AP];  // f16 h rows, full K=256
  __shared__ int ridS[MT];
  int tid = threadIdx.x;
  int lane = tid & 63;
  int wv = tid >> 6;
  int r16 = lane & 15;
  int kg = lane >> 4;
  int ntiles = (cs + MT - 1) / MT;
  float vb[2][4];
#pragma unroll
  for (int jt = 0; jt < 2; ++jt) {
    int j = wv * 32 + jt * 16 + r16;
    vb[jt][0] = ldf(bir, wf32, j);
    vb[jt][1] = ldf(biz, wf32, j);
    vb[jt][2] = ldf(bin_, wf32, j);
    vb[jt][3] = ldf(bhn, wf32, j);
  }
  const s8_t* WB = (const s8_t*)WhB;  // 16B fragments

  for (int tile = blockIdx.x; tile < ntiles; tile += gridDim.x) {
    __syncthreads();  // As/ridS reuse safe (prev epilogue done)
    {  // stage A: 16 threads/row, 16 f16 elements each
      int i = tid >> 4;
      int seg = tid & 15;
      int idx = tile * MT + i;
      int rid = (idx < cs) ? (int)list[idx] : -1;
      if (seg == 0) ridS[i] = rid;
      u16* dst = As + i * AP + seg * 16;
      if (rid >= 0) {
        if (s == 0) {
#pragma unroll
          for (int q = 0; q < 4; ++q) {
            us4_t hb;
#pragma unroll
            for (int e = 0; e < 4; ++e) {
              _Float16 hh = (_Float16)ldf(h0, wf32, (size_t)rid * H + seg * 16 + q * 4 + e);
              hb[e] = __builtin_bit_cast(u16, hh);
            }
            *(us4_t*)(dst + q * 4) = hb;
          }
        } else {
          const float* src = out + (size_t)(rid - BA) * H + seg * 16;
#pragma unroll
          for (int q = 0; q < 4; ++q) {
            f4_t v = *(const f4_t*)(src + q * 4);
            us4_t hb;
#pragma unroll
            for (int e = 0; e < 4; ++e) {
              _Float16 hh = (_Float16)v[e];
              hb[e] = __builtin_bit_cast(u16, hh);
            }
            *(us4_t*)(dst + q * 4) = hb;
          }
        }
      } else {
        us4_t hz; hz[0] = 0; hz[1] = 0; hz[2] = 0; hz[3] = 0;
#pragma unroll
        for (int q = 0; q < 4; ++q) *(us4_t*)(dst + q * 4) = hz;
      }
    }
    __syncthreads();

    f4_t acc[2][6];
#pragma unroll
    for (int a = 0; a < 2; ++a)
#pragma unroll
      for (int b = 0; b < 6; ++b) acc[a][b] = (f4_t)0.0f;

#pragma unroll 2
    for (int kk = 0; kk < 8; ++kk) {
      h8_t af[2];
#pragma unroll
      for (int mt = 0; mt < 2; ++mt)
        af[mt] = __builtin_bit_cast(h8_t,
            *(const s8_t*)(As + (mt * 16 + r16) * AP + kk * 32 + kg * 8));
      s8_t bfr[6];
#pragma unroll
      for (int g = 0; g < 3; ++g)
#pragma unroll
        for (int jt = 0; jt < 2; ++jt) {
          int cg = g * 16 + wv * 2 + jt;
          bfr[g * 2 + jt] = WB[(size_t)((kk * 48 + cg) * 64 + lane)];
        }
#pragma unroll
      for (int c = 0; c < 6; ++c)
#pragma unroll
        for (int mt = 0; mt < 2; ++mt)
          acc[mt][c] = __builtin_amdgcn_mfma_f32_16x16x32_f16(
              af[mt], __builtin_bit_cast(h8_t, bfr[c]), acc[mt][c], 0, 0, 0);
    }

    // epilogue: row = mt*16 + kg*4 + r, col = wv*32 + jt*16 + r16
#pragma unroll
    for (int mt = 0; mt < 2; ++mt)
#pragma unroll
      for (int r = 0; r < 4; ++r) {
        int rowl = mt * 16 + kg * 4 + r;
        int rid = ridS[rowl];
        if (rid < 0) continue;
#pragma unroll
        for (int jt = 0; jt < 2; ++jt) {
          int j = wv * 32 + jt * 16 + r16;
          size_t xb = (size_t)rid * TH + j;
          float rg = sigm(bf2f(xproj[xb]) + vb[jt][0] + acc[mt][jt][r]);
          float zg = sigm(bf2f(xproj[xb + H]) + vb[jt][1] + acc[mt][2 + jt][r]);
          float ng = tanh_(bf2f(xproj[xb + 2 * H]) + vb[jt][2] + rg * (acc[mt][4 + jt][r] + vb[jt][3]));
          float hp = (s == 0) ? ldf(h0, wf32, (size_t)rid * H + j)
                              : out[(size_t)(rid - BA) * H + j];
          out[(size_t)rid * H + j] = (1.0f - zg) * ng + zg * hp;
        }
      }
  }
}

// ---- scan helpers (register-resident f16 weights; used by kscan + ktail) ----
#define LDW(VR, P, c) { uint4 q_ = *(const uint4*)((P) + (c) * 8); \
  VR[(c)*4+0] = q_.x; VR[(c)*4+1] = q_.y; VR[(c)*4+2] = q_.z; VR[(c)*4+3] = q_.w; }
#define LDWALL(VR, P) \
  LDW(VR,P,0) LDW(VR,P,1) LDW(VR,P,2) LDW(VR,P,3) LDW(VR,P,4) LDW(VR,P,5) LDW(VR,P,6) LDW(VR,P,7) \
  LDW(VR,P,8) LDW(VR,P,9) LDW(VR,P,10) LDW(VR,P,11) LDW(VR,P,12) LDW(VR,P,13) LDW(VR,P,14) LDW(VR,P,15)

#define BCH(x) __builtin_bit_cast(h2_t, (u32)(x))
#define DOTC(c) { uint4 hv_ = h4_[c]; \
  h2_t a0_ = __builtin_bit_cast(h2_t, hv_.x); \
  h2_t a1_ = __builtin_bit_cast(h2_t, hv_.y); \
  h2_t a2_ = __builtin_bit_cast(h2_t, hv_.z); \
  h2_t a3_ = __builtin_bit_cast(h2_t, hv_.w); \
  ar = F2(BCH(WR[4*(c)+0]), a0_, ar); az = F2(BCH(WZ[4*(c)+0]), a0_, az); an = F2(BCH(WN[4*(c)+0]), a0_, an); \
  ar = F2(BCH(WR[4*(c)+1]), a1_, ar); az = F2(BCH(WZ[4*(c)+1]), a1_, az); an = F2(BCH(WN[4*(c)+1]), a1_, an); \
  ar = F2(BCH(WR[4*(c)+2]), a2_, ar); az = F2(BCH(WZ[4*(c)+2]), a2_, az); an = F2(BCH(WN[4*(c)+2]), a2_, an); \
  ar = F2(BCH(WR[4*(c)+3]), a3_, ar); az = F2(BCH(WZ[4*(c)+3]), a3_, az); an = F2(BCH(WN[4*(c)+3]), a3_, an); }
#define DOT16 \
  DOTC(0) DOTC(1) DOTC(2) DOTC(3) DOTC(4) DOTC(5) DOTC(6) DOTC(7) \
  DOTC(8) DOTC(9) DOTC(10) DOTC(11) DOTC(12) DOTC(13) DOTC(14) DOTC(15)

// deep tail: rows with d >= NBUCK, processed serially per chain
__global__ __launch_bounds__(512, 2) void ktail(const u16* __restrict__ xproj,
                                                float* __restrict__ out,
                                                const u16* __restrict__ WhF,
                                                const unsigned char* __restrict__ dbuf,
                                                const void* __restrict__ bir, const void* __restrict__ biz,
                                                const void* __restrict__ bin_, const void* __restrict__ bhn,
                                                const int* __restrict__ flags) {
  int w = blockIdx.x;
  int tid = threadIdx.x;
  int j = tid >> 1;
  int half = tid & 1;
  bool wf32 = flags[2] != 0;
  __shared__ __align__(16) u16 hsb[256];
  __shared__ unsigned char dcol[1024];
  for (int t = tid; t < 1024; t += 512) dcol[t] = dbuf[(size_t)w * 1024 + t];
  const u16* pr = WhF + (size_t)j * H + half * 128;
  const u16* pz = WhF + (size_t)H * H + (size_t)j * H + half * 128;
  const u16* pn = WhF + (size_t)2 * H * H + (size_t)j * H + half * 128;
  v64u WR, WZ, WN;
  LDWALL(WR, pr)
  LDWALL(WZ, pz)
  LDWALL(WN, pn)
  float vbir = ldf(bir, wf32, j), vbiz = ldf(biz, wf32, j);
  float vbin = ldf(bin_, wf32, j), vbhn = ldf(bhn, wf32, j);
  __syncthreads();
  int prev_t = -99;
  float hreg = 0.0f;
#pragma unroll 1
  for (int t = 0; t < 1024; ++t) {
    int d = dcol[t];
    if (d < NBUCK || d == 255) continue;  // uniform across block
    if (prev_t != t - 1) {
      hreg = out[((size_t)(t - 1) * BA + w) * H + j];
      if (half == 0) { _Float16 hh = (_Float16)hreg; hsb[j] = __builtin_bit_cast(u16, hh); }
      __syncthreads();
    }
    const uint4* h4_ = (const uint4*)(&hsb[half * 128]);
    float ar = 0.0f, az = 0.0f, an = 0.0f;
    DOT16
    ar += __shfl_xor(ar, 1, 64);
    az += __shfl_xor(az, 1, 64);
    an += __shfl_xor(an, 1, 64);
    size_t xb = ((size_t)t * BA + w) * TH + j;
    float r = sigm(bf2f(xproj[xb]) + vbir + ar);
    float z = sigm(bf2f(xproj[xb + H]) + vbiz + az);
    float n = tanh_(bf2f(xproj[xb + 2 * H]) + vbin + r * (an + vbhn));
    float hnew = (1.0f - z) * n + z * hreg;
    if (half == 0) out[((size_t)t * BA + w) * H + j] = hnew;
    __syncthreads();
    if (half == 0) { _Float16 hh = (_Float16)hnew; hsb[j] = __builtin_bit_cast(u16, hh); }
    hreg = hnew;
    prev_t = t;
    __syncthreads();
  }
}

// ---- fallback serial scan (used only when workspace can't hold full xproj) ----
__global__ __launch_bounds__(512, 2) void kscan(
    const u16* __restrict__ xproj, const void* __restrict__ resets,
    const void* __restrict__ h0, float* __restrict__ carry,
    const u16* __restrict__ WhF,
    const void* __restrict__ bir, const void* __restrict__ biz, const void* __restrict__ bin_,
    const void* __restrict__ bhn, float* __restrict__ out, int t0, int Tc,
    const int* __restrict__ flags) {
  int w = blockIdx.x;
  int tid = threadIdx.x;
  int j = tid >> 1;
  int half = tid & 1;
  bool wf32 = flags[2] != 0;
  bool rbyte = flags[1] != 0;
  __shared__ __align__(16) u16 hsb[2][256];
  __shared__ int rstS[1024];

  for (int t = tid; t < Tc; t += 512)
    rstS[t] = ldrst(resets, rbyte, (size_t)(t0 + t) * BA + w);

  const u16* pr = WhF + (size_t)j * H + half * 128;
  const u16* pz = WhF + (size_t)H * H + (size_t)j * H + half * 128;
  const u16* pn = WhF + (size_t)2 * H * H + (size_t)j * H + half * 128;
  v64u WR, WZ, WN;
  LDWALL(WR, pr)
  LDWALL(WZ, pz)
  LDWALL(WN, pn)

  float vbir = ldf(bir, wf32, j), vbiz = ldf(biz, wf32, j);
  float vbin = ldf(bin_, wf32, j), vbhn = ldf(bhn, wf32, j);

  float hreg = (t0 == 0) ? ldf(h0, wf32, (size_t)w * H + j) : carry[(size_t)w * H + j];
  __syncthreads();
  if (rstS[0] != 0) hreg = 0.0f;
  if (half == 0) {
    _Float16 hh = (_Float16)hreg;
    hsb[0][j] = __builtin_bit_cast(u16, hh);
  }
  __syncthreads();

  size_t xb0 = (size_t)w * TH + j;
  u16 cxr = xproj[xb0], cxz = xproj[xb0 + H], cxn = xproj[xb0 + 2 * H];

#pragma unroll 1
  for (int tl = 0; tl < Tc; ++tl) {
    u16 nxr = 0, nxz = 0, nxn = 0;
    if (tl + 1 < Tc) {
      size_t nb = ((size_t)(tl + 1) * BA + w) * TH + j;
      nxr = xproj[nb]; nxz = xproj[nb + H]; nxn = xproj[nb + 2 * H];
    }
    const uint4* h4_ = (const uint4*)(&hsb[tl & 1][half * 128]);
    float ar = 0.0f, az = 0.0f, an = 0.0f;
    DOT16
    ar += __shfl_xor(ar, 1, 64);
    az += __shfl_xor(az, 1, 64);
    an += __shfl_xor(an, 1, 64);
    float r = sigm(bf2f(cxr) + vbir + ar);
    float z = sigm(bf2f(cxz) + vbiz + az);
    float n = tanh_(bf2f(cxn) + vbin + r * (an + vbhn));
    float hnew = (1.0f - z) * n + z * hreg;
    if (half == 0) out[((size_t)(t0 + tl) * BA + w) * H + j] = hnew;

    float hnext = hnew;
    if (tl + 1 < Tc && rstS[tl + 1] != 0) hnext = 0.0f;
    if (half == 0) {
      _Float16 hh = (_Float16)hnext;
      hsb[(tl & 1) ^ 1][j] = __builtin_bit_cast(u16, hh);
    }
    hreg = hnext;
    cxr = nxr; cxz = nxz; cxn = nxn;
    __syncthreads();
  }
  if (half == 0) carry[(size_t)w * H + j] = hreg;
}

extern "C" void kernel_launch(void* const* d_in, const int* in_sizes, int n_in,
                              void* d_out, int out_size, void* d_ws, size_t ws_size,
                              hipStream_t stream) {
  const void* ins = d_in[0];
  const void* resets = d_in[1];
  const void* h0 = d_in[2];
  const void* Wir = d_in[3];
  const void* Wiz = d_in[4];
  const void* Win = d_in[5];
  const void* bir = d_in[6];
  const void* biz = d_in[7];
  const void* bin_ = d_in[8];
  const void* Whr = d_in[9];
  const void* Whz = d_in[10];
  const void* Whn = d_in[11];
  const void* bhn = d_in[12];
  float* out = (float*)d_out;

  // ws: [flags][WT 768KB][carry 128KB][cnt 256B][dbuf 128KB][lists 2MB][WhB 384KB][insb 64MB?][xproj]
  const size_t off_wt = 256;
  const size_t wt_bytes = (size_t)6 * H * H * 2;
  const size_t off_carry = off_wt + wt_bytes;
  const size_t off_cnt = off_carry + (size_t)BA * H * 4;
  const size_t off_dbuf = off_cnt + 256;
  const size_t off_list = off_dbuf + NROWS;
  const size_t off_whb = off_list + (size_t)NBUCK * LCAP * 4;
  const size_t whb_bytes = (size_t)TH * H * 2;
  const size_t off_insb = off_whb + whb_bytes;
  const size_t insb_bytes = (size_t)1024 * BA * H * 2;
  const size_t chunk_bytes = (size_t)BA * TH * 2;

  int* flags = (int*)d_ws;
  u16* WT = (u16*)((char*)d_ws + off_wt);
  float* carry = (float*)((char*)d_ws + off_carry);
  int* cnt = (int*)((char*)d_ws + off_cnt);
  unsigned char* dbuf = (unsigned char*)((char*)d_ws + off_dbuf);
  u32* list = (u32*)((char*)d_ws + off_list);
  u16* WhB = (u16*)((char*)d_ws + off_whb);
  u16* insb = (u16*)((char*)d_ws + off_insb);

  int use_insb = (ws_size >= off_insb + insb_bytes + (size_t)1024 * chunk_bytes) ? 1 : 0;
  size_t off_xproj = use_insb ? (off_insb + insb_bytes) : off_insb;
  u16* xproj = (u16*)((char*)d_ws + off_xproj);

  kdetect<<<1, 256, 0, stream>>>((const u32*)ins, (const u32*)resets,
                                 (const u32*)Whr, (const u32*)Wir, flags, cnt);
  if (use_insb) kprep<<<16384, 256, 0, stream>>>(ins, insb, flags);
  ktrans<<<dim3(4, 4, 6), 256, 0, stream>>>(Wir, Wiz, Win, Whr, Whz, Whn, WT, flags);
  kswz<<<96, 256, 0, stream>>>(WT, WhB);

  const u16* WhT = WT + (size_t)3 * H * H;
  if (ws_size >= off_xproj + (size_t)1024 * chunk_bytes) {
    // segment-parallel path: full xproj, then process rows by reset-distance d
    kdlists<<<128, 256, 0, stream>>>(resets, dbuf, cnt, list, flags);
    kgemm<<<dim3(1024, 6), 256, 0, stream>>>(ins, insb, use_insb, 0, WT, xproj, flags);
    kelem<<<1024, 256, 0, stream>>>(xproj, resets, out, bir, biz, bin_, bhn, flags);
    for (int s = 0; s < NBUCK; ++s)
      kstep<<<1024, 512, 0, stream>>>(xproj, out, h0, WhB, cnt, list + (size_t)s * LCAP,
                                      bir, biz, bin_, bhn, flags, s);
    ktail<<<128, 512, 0, stream>>>(xproj, out, WhT, dbuf, bir, biz, bin_, bhn, flags);
  } else {
    // fallback: chunked serial scan
    int Tc = 1024;
    while (Tc > 1 && off_xproj + (size_t)Tc * chunk_bytes > ws_size) Tc >>= 1;
    int nchunks = 1024 / Tc;
    for (int c = 0; c < nchunks; ++c) {
      int t0 = c * Tc;
      kgemm<<<dim3(Tc, 6), 256, 0, stream>>>(ins, insb, use_insb, t0, WT, xproj, flags);
      kscan<<<128, 512, 0, stream>>>(xproj, resets, h0, carry, WhT,
                                     bir, biz, bin_, bhn, out, t0, Tc, flags);
    }
  }
}

// Round 6
// 731.323 us; speedup vs baseline: 1.7337x; 1.0665x over previous
//
#include <hip/hip_runtime.h>

#define BA 128
#define H 256
#define TH 768
#define NROWS (1024 * BA)
#define LCAP 65536
#define NBUCK 8
#define MT 32
#define AP 264
#define NFRAG (8 * 48 * 64)  // fragments per part (24576)

typedef _Float16 h2_t __attribute__((ext_vector_type(2)));
typedef _Float16 h8_t __attribute__((ext_vector_type(8)));
typedef short s8_t __attribute__((ext_vector_type(8)));
typedef float f4_t __attribute__((ext_vector_type(4)));
typedef unsigned short u16;
typedef u16 us4_t __attribute__((ext_vector_type(4)));
typedef unsigned int u32;
typedef u32 v64u __attribute__((ext_vector_type(64)));

__device__ __forceinline__ float bf2f(u16 u) {
  union { u32 i; float f; } c; c.i = ((u32)u) << 16; return c.f;
}
__device__ __forceinline__ u16 f2bf(float f) {
  union { float f; u32 i; } c; c.f = f;
  u32 r = c.i + 0x7FFFu + ((c.i >> 16) & 1u);
  return (u16)(r >> 16);
}
__device__ __forceinline__ float sigm(float x) {
  float e = __builtin_amdgcn_exp2f(-x * 1.442695040888963f);
  return __builtin_amdgcn_rcpf(1.0f + e);
}
__device__ __forceinline__ float tanh_(float x) {
  float e = __builtin_amdgcn_exp2f(x * 2.885390081777927f);
  return 1.0f - 2.0f * __builtin_amdgcn_rcpf(1.0f + e);
}
__device__ __forceinline__ float ldf(const void* p, bool f32, size_t idx) {
  return f32 ? ((const float*)p)[idx] : bf2f(((const u16*)p)[idx]);
}
__device__ __forceinline__ int ldrst(const void* p, bool isbyte, size_t idx) {
  return isbyte ? (int)((const unsigned char*)p)[idx] : ((const int*)p)[idx];
}
__device__ __forceinline__ float F2(h2_t a, h2_t b, float c) {
#if defined(__has_builtin) && __has_builtin(__builtin_amdgcn_fdot2)
  return __builtin_amdgcn_fdot2(a, b, c, false);
#else
  return c + (float)a[0] * (float)b[0] + (float)a[1] * (float)b[1];
#endif
}

// flags: [0]=ins_f32 [1]=resets_byte [2]=Wh_f32 [3]=Wi_f32
__global__ __launch_bounds__(256) void kdetect(const u32* __restrict__ insw,
                                               const u32* __restrict__ rstw,
                                               const u32* __restrict__ whrw,
                                               const u32* __restrict__ wirw,
                                               int* __restrict__ flags,
                                               int* __restrict__ cnt) {
  __shared__ int c0, c1, c2, c3;
  if (threadIdx.x == 0) { c0 = 0; c1 = 0; c2 = 0; c3 = 0; }
  if (threadIdx.x < NBUCK) cnt[threadIdx.x] = 0;
  __syncthreads();
  if (!(fabsf(bf2f((u16)(insw[threadIdx.x] & 0xFFFFu))) < 1e10f)) atomicAdd(&c0, 1);
  if (!(fabsf(bf2f((u16)(whrw[threadIdx.x] & 0xFFFFu))) < 1e10f)) atomicAdd(&c2, 1);
  if (!(fabsf(bf2f((u16)(wirw[threadIdx.x] & 0xFFFFu))) < 1e10f)) atomicAdd(&c3, 1);
  if (threadIdx.x < 128 && rstw[threadIdx.x] > 1u) atomicAdd(&c1, 1);
  __syncthreads();
  if (threadIdx.x == 0) {
    flags[0] = (c0 > 8) ? 1 : 0;
    flags[1] = (c1 > 0) ? 1 : 0;
    flags[2] = (c2 > 8) ? 1 : 0;
    flags[3] = (c3 > 8) ? 1 : 0;
  }
}

// WT[g][j][k] = W_g[k][j]; g=0..2 (Wi): bf16 for MFMA; g=3..5 (Wh): f16
__global__ __launch_bounds__(256) void ktrans(const void* __restrict__ W0, const void* __restrict__ W1,
                                              const void* __restrict__ W2, const void* __restrict__ W3,
                                              const void* __restrict__ W4, const void* __restrict__ W5,
                                              u16* __restrict__ WT, const int* __restrict__ flags) {
  __shared__ u16 tile[64][65];
  int g = blockIdx.z;
  bool f32in = ((g < 3) ? flags[3] : flags[2]) != 0;
  bool toF16 = (g >= 3);
  const void* srcs[6] = {W0, W1, W2, W3, W4, W5};
  const void* src = srcs[g];
  int k0 = blockIdx.x * 64, j0 = blockIdx.y * 64;
  int tid = threadIdx.x;
#pragma unroll
  for (int p = 0; p < 16; ++p) {
    int e = p * 256 + tid;
    int kr = e >> 6, jc = e & 63;
    size_t idx = (size_t)(k0 + kr) * H + j0 + jc;
    float v = f32in ? ((const float*)src)[idx] : bf2f(((const u16*)src)[idx]);
    u16 bits;
    if (toF16) {
      _Float16 h = (_Float16)v;
      bits = __builtin_bit_cast(u16, h);
    } else {
      bits = f2bf(v);
    }
    tile[kr][jc] = bits;
  }
  __syncthreads();
  u16* dst = WT + (size_t)g * H * H;
#pragma unroll
  for (int p = 0; p < 16; ++p) {
    int e = p * 256 + tid;
    int jr = e >> 6, kc = e & 63;
    dst[(size_t)(j0 + jr) * H + k0 + kc] = tile[kc][jr];
  }
}

// WB: MFMA-fragment-ordered weights. part0 = Wi (bf16, gates 0..2), part1 = Wh
// (f16, gates 3..5). fragment fl=(kk*48+cg)*64+lane of part p holds
// W_g^T[col=(cg&15)*16+(lane&15)][k=kk*32+(lane>>4)*8 .. +8], g=p*3+(cg>>4).
// Grid dim3(96, 2): blockIdx.y = part (NFRAG=24576 is not a power of two --
// the round-5 `f >> 14` split corrupted both tables).
__global__ __launch_bounds__(256) void kswz(const u16* __restrict__ WT, u16* __restrict__ WB) {
  int fl = blockIdx.x * 256 + threadIdx.x;  // 0..24575
  if (fl >= NFRAG) return;
  int part = blockIdx.y;
  int lane = fl & 63;
  int cg = (fl >> 6) % 48;
  int kk = (fl >> 6) / 48;
  int g = part * 3 + (cg >> 4);
  int col = ((cg & 15) << 4) + (lane & 15);
  int k0 = kk * 32 + ((lane >> 4) << 3);
  const u16* src = WT + (size_t)g * H * H + (size_t)col * H + k0;
  *(s8_t*)(WB + ((size_t)part * NFRAG + fl) * 8) = *(const s8_t*)src;
}

// xproj[m, g*256+j] = ins[m,:] @ W_ig[:,j] -> bf16.
// One block per timestep: full 128x256 A staged once in LDS (f32->bf16 inline,
// absorbs the old kprep round-trip); B direct from L2 in fragment order (WiB).
// Waves tile 2x2 over (rows,cols): each B fragment feeds 4 MFMAs.
__global__ __launch_bounds__(256) void kgemm(const void* __restrict__ ins,
                                             int t0, const u16* __restrict__ WiB,
                                             u16* __restrict__ C,
                                             const int* __restrict__ flags) {
  __shared__ __align__(16) u16 As[128 * AP];
  bool f32in = flags[0] != 0;
  int tid = threadIdx.x;
  int bt = blockIdx.x;
  size_t abase = (size_t)(t0 + bt) * BA * H;
#pragma unroll
  for (int q = 0; q < 16; ++q) {  // linear stage: 256 thr x 8 u16, coalesced
    int idx = q * 256 + tid;      // 0..4095
    int row = idx >> 5;
    int col0 = (idx & 31) * 8;
    s8_t v;
    if (f32in) {
      const float* s = (const float*)ins + abase + (size_t)idx * 8;
      f4_t x0 = *(const f4_t*)s;
      f4_t x1 = *(const f4_t*)(s + 4);
#pragma unroll
      for (int i = 0; i < 4; ++i) v[i] = (short)f2bf(x0[i]);
#pragma unroll
      for (int i = 0; i < 4; ++i) v[4 + i] = (short)f2bf(x1[i]);
    } else {
      v = *(const s8_t*)((const u16*)ins + abase + (size_t)idx * 8);
    }
    *(s8_t*)(As + row * AP + col0) = v;
  }
  __syncthreads();

  int lane = tid & 63;
  int wv = tid >> 6;
  int wr = wv >> 1;   // row group (64 rows)
  int wc = wv & 1;    // col group (64 cols within 128-chunk)
  int r16 = lane & 15;
  int kg = lane >> 4;
  const s8_t* WB = (const s8_t*)WiB;
  int row0 = bt * 128;

  for (int c = 0; c < 6; ++c) {
    f4_t acc[4][4];
#pragma unroll
    for (int a = 0; a < 4; ++a)
#pragma unroll
      for (int b = 0; b < 4; ++b) acc[a][b] = (f4_t)0.0f;
#pragma unroll 2
    for (int kk = 0; kk < 8; ++kk) {
      s8_t af[4];
#pragma unroll
      for (int mt = 0; mt < 4; ++mt)
        af[mt] = *(const s8_t*)(As + (wr * 64 + mt * 16 + r16) * AP + kk * 32 + kg * 8);
      s8_t bfr[4];
#pragma unroll
      for (int ct = 0; ct < 4; ++ct) {
        int cg = c * 8 + wc * 4 + ct;
        bfr[ct] = WB[(size_t)((kk * 48 + cg) * 64 + lane)];
      }
#pragma unroll
      for (int ct = 0; ct < 4; ++ct)
#pragma unroll
        for (int mt = 0; mt < 4; ++mt)
          acc[mt][ct] = __builtin_amdgcn_mfma_f32_16x16x32_bf16(af[mt], bfr[ct], acc[mt][ct], 0, 0, 0);
    }
#pragma unroll
    for (int mt = 0; mt < 4; ++mt)
#pragma unroll
      for (int ct = 0; ct < 4; ++ct)
#pragma unroll
        for (int r = 0; r < 4; ++r) {
          int grow = row0 + wr * 64 + mt * 16 + kg * 4 + r;
          int gcol = c * 128 + wc * 64 + ct * 16 + r16;
          C[(size_t)grow * TH + gcol] = f2bf(acc[mt][ct][r]);
        }
  }
}

// ---- segment-level machinery ----------------------------------------------
// One block per chain w. Reset column in LDS; walk-back in LDS; one global
// atomicAdd per (block, bucket). dbuf layout: [w][t] (coalesced here + ktail).
__global__ __launch_bounds__(256) void kdlists(const void* __restrict__ resets,
                                               unsigned char* __restrict__ dbuf,
                                               int* __restrict__ cnt,
                                               u32* __restrict__ list,
                                               const int* __restrict__ flags) {
  bool rbyte = flags[1] != 0;
  int w = blockIdx.x;  // 128 blocks
  int tid = threadIdx.x;
  __shared__ unsigned char rst[1024];
  __shared__ unsigned char dS[1024];
  __shared__ int lcnt[NBUCK], lbase[NBUCK], lpos[NBUCK];
  if (tid < NBUCK) { lcnt[tid] = 0; lpos[tid] = 0; }
  for (int t = tid; t < 1024; t += 256)
    rst[t] = (unsigned char)(ldrst(resets, rbyte, (size_t)t * BA + w) != 0);
  __syncthreads();
#pragma unroll
  for (int p = 0; p < 4; ++p) {
    int t = p * 256 + tid;
    int d;
    if (rst[t]) {
      d = 255;
    } else {
      int tr = t - 1;
      while (tr >= 0 && !rst[tr]) --tr;
      d = t - ((tr >= 0) ? tr : 0);
      if (d > 254) d = 254;
    }
    dS[t] = (unsigned char)d;
    if (d < NBUCK) atomicAdd(&lcnt[d], 1);
  }
  __syncthreads();
  if (tid < NBUCK) lbase[tid] = atomicAdd(&cnt[tid], lcnt[tid]);
  for (int t = tid; t < 1024; t += 256) dbuf[(size_t)w * 1024 + t] = dS[t];
  __syncthreads();
#pragma unroll
  for (int p = 0; p < 4; ++p) {
    int t = p * 256 + tid;
    int d = dS[t];
    if (d < NBUCK) {
      int pos = lbase[d] + atomicAdd(&lpos[d], 1);
      if (pos < LCAP) list[(size_t)d * LCAP + pos] = (u32)(t * BA + w);
    }
  }
}

// all reset rows: h_prev = 0 -> pure elementwise from xproj
__global__ __launch_bounds__(256) void kelem(const u16* __restrict__ xproj,
                                             const void* __restrict__ resets,
                                             float* __restrict__ out,
                                             const void* __restrict__ bir, const void* __restrict__ biz,
                                             const void* __restrict__ bin_, const void* __restrict__ bhn,
                                             const int* __restrict__ flags) {
  bool rbyte = flags[1] != 0;
  bool wf32 = flags[2] != 0;
  int j = threadIdx.x;
  float vbir = ldf(bir, wf32, j), vbiz = ldf(biz, wf32, j);
  float vbin = ldf(bin_, wf32, j), vbhn = ldf(bhn, wf32, j);
  for (int i = blockIdx.x; i < NROWS; i += gridDim.x) {
    if (!ldrst(resets, rbyte, i)) continue;
    size_t xb = (size_t)i * TH + j;
    float r = sigm(bf2f(xproj[xb]) + vbir);
    float z = sigm(bf2f(xproj[xb + H]) + vbiz);
    float n = tanh_(bf2f(xproj[xb + 2 * H]) + vbin + r * vbhn);
    out[(size_t)i * H + j] = (1.0f - z) * n;
  }
}

// one d-level: gather h_prev rows into LDS (f16, full K), B direct from L2 in
// fragment order (WhB) -> no B staging, 2 barriers/tile, M=32 tiles.
// NOTE: no min-waves clause -- forcing occupancy caused VGPR=64 + scratch
// spills (WRITE_SIZE 404 MB, round 2). ~110 VGPR natural => 2 blocks/CU.
__global__ __launch_bounds__(512) void kstep(const u16* __restrict__ xproj,
                                             float* __restrict__ out,
                                             const void* __restrict__ h0,
                                             const u16* __restrict__ WhB,
                                             const int* __restrict__ cnt,
                                             const u32* __restrict__ list,
                                             const void* __restrict__ bir, const void* __restrict__ biz,
                                             const void* __restrict__ bin_, const void* __restrict__ bhn,
                                             const int* __restrict__ flags, int s) {
  int cs = cnt[s];
  if (cs <= 0) return;
  bool wf32 = flags[2] != 0;
  __shared__ __align__(16) u16 As[MT * AP];  // f16 h rows, full K=256
  __shared__ int ridS[MT];
  int tid = threadIdx.x;
  int lane = tid & 63;
  int wv = tid >> 6;
  int r16 = lane & 15;
  int kg = lane >> 4;
  int ntiles = (cs + MT - 1) / MT;
  float vb[2][4];
#pragma unroll
  for (int jt = 0; jt < 2; ++jt) {
    int j = wv * 32 + jt * 16 + r16;
    vb[jt][0] = ldf(bir, wf32, j);
    vb[jt][1] = ldf(biz, wf32, j);
    vb[jt][2] = ldf(bin_, wf32, j);
    vb[jt][3] = ldf(bhn, wf32, j);
  }
  const s8_t* WB = (const s8_t*)WhB;  // 16B fragments

  for (int tile = blockIdx.x; tile < ntiles; tile += gridDim.x) {
    __syncthreads();  // As/ridS reuse safe (prev epilogue done)
    {  // stage A: 16 threads/row, 16 f16 elements each
      int i = tid >> 4;
      int seg = tid & 15;
      int idx = tile * MT + i;
      int rid = (idx < cs) ? (int)list[idx] : -1;
      if (seg == 0) ridS[i] = rid;
      u16* dst = As + i * AP + seg * 16;
      if (rid >= 0) {
        if (s == 0) {
#pragma unroll
          for (int q = 0; q < 4; ++q) {
            us4_t hb;
#pragma unroll
            for (int e = 0; e < 4; ++e) {
              _Float16 hh = (_Float16)ldf(h0, wf32, (size_t)rid * H + seg * 16 + q * 4 + e);
              hb[e] = __builtin_bit_cast(u16, hh);
            }
            *(us4_t*)(dst + q * 4) = hb;
          }
        } else {
          const float* src = out + (size_t)(rid - BA) * H + seg * 16;
#pragma unroll
          for (int q = 0; q < 4; ++q) {
            f4_t v = *(const f4_t*)(src + q * 4);
            us4_t hb;
#pragma unroll
            for (int e = 0; e < 4; ++e) {
              _Float16 hh = (_Float16)v[e];
              hb[e] = __builtin_bit_cast(u16, hh);
            }
            *(us4_t*)(dst + q * 4) = hb;
          }
        }
      } else {
        us4_t hz; hz[0] = 0; hz[1] = 0; hz[2] = 0; hz[3] = 0;
#pragma unroll
        for (int q = 0; q < 4; ++q) *(us4_t*)(dst + q * 4) = hz;
      }
    }
    __syncthreads();

    f4_t acc[2][6];
#pragma unroll
    for (int a = 0; a < 2; ++a)
#pragma unroll
      for (int b = 0; b < 6; ++b) acc[a][b] = (f4_t)0.0f;

#pragma unroll 2
    for (int kk = 0; kk < 8; ++kk) {
      h8_t af[2];
#pragma unroll
      for (int mt = 0; mt < 2; ++mt)
        af[mt] = __builtin_bit_cast(h8_t,
            *(const s8_t*)(As + (mt * 16 + r16) * AP + kk * 32 + kg * 8));
      s8_t bfr[6];
#pragma unroll
      for (int g = 0; g < 3; ++g)
#pragma unroll
        for (int jt = 0; jt < 2; ++jt) {
          int cg = g * 16 + wv * 2 + jt;
          bfr[g * 2 + jt] = WB[(size_t)((kk * 48 + cg) * 64 + lane)];
        }
#pragma unroll
      for (int c = 0; c < 6; ++c)
#pragma unroll
        for (int mt = 0; mt < 2; ++mt)
          acc[mt][c] = __builtin_amdgcn_mfma_f32_16x16x32_f16(
              af[mt], __builtin_bit_cast(h8_t, bfr[c]), acc[mt][c], 0, 0, 0);
    }

    // epilogue: row = mt*16 + kg*4 + r, col = wv*32 + jt*16 + r16
#pragma unroll
    for (int mt = 0; mt < 2; ++mt)
#pragma unroll
      for (int r = 0; r < 4; ++r) {
        int rowl = mt * 16 + kg * 4 + r;
        int rid = ridS[rowl];
        if (rid < 0) continue;
#pragma unroll
        for (int jt = 0; jt < 2; ++jt) {
          int j = wv * 32 + jt * 16 + r16;
          size_t xb = (size_t)rid * TH + j;
          float rg = sigm(bf2f(xproj[xb]) + vb[jt][0] + acc[mt][jt][r]);
          float zg = sigm(bf2f(xproj[xb + H]) + vb[jt][1] + acc[mt][2 + jt][r]);
          float ng = tanh_(bf2f(xproj[xb + 2 * H]) + vb[jt][2] + rg * (acc[mt][4 + jt][r] + vb[jt][3]));
          float hp = (s == 0) ? ldf(h0, wf32, (size_t)rid * H + j)
                              : out[(size_t)(rid - BA) * H + j];
          out[(size_t)rid * H + j] = (1.0f - zg) * ng + zg * hp;
        }
      }
  }
}

// ---- scan helpers (register-resident f16 weights; used by kscan + ktail) ----
#define LDW(VR, P, c) { uint4 q_ = *(const uint4*)((P) + (c) * 8); \
  VR[(c)*4+0] = q_.x; VR[(c)*4+1] = q_.y; VR[(c)*4+2] = q_.z; VR[(c)*4+3] = q_.w; }
#define LDWALL(VR, P) \
  LDW(VR,P,0) LDW(VR,P,1) LDW(VR,P,2) LDW(VR,P,3) LDW(VR,P,4) LDW(VR,P,5) LDW(VR,P,6) LDW(VR,P,7) \
  LDW(VR,P,8) LDW(VR,P,9) LDW(VR,P,10) LDW(VR,P,11) LDW(VR,P,12) LDW(VR,P,13) LDW(VR,P,14) LDW(VR,P,15)

#define BCH(x) __builtin_bit_cast(h2_t, (u32)(x))
#define DOTC(c) { uint4 hv_ = h4_[c]; \
  h2_t a0_ = __builtin_bit_cast(h2_t, hv_.x); \
  h2_t a1_ = __builtin_bit_cast(h2_t, hv_.y); \
  h2_t a2_ = __builtin_bit_cast(h2_t, hv_.z); \
  h2_t a3_ = __builtin_bit_cast(h2_t, hv_.w); \
  ar = F2(BCH(WR[4*(c)+0]), a0_, ar); az = F2(BCH(WZ[4*(c)+0]), a0_, az); an = F2(BCH(WN[4*(c)+0]), a0_, an); \
  ar = F2(BCH(WR[4*(c)+1]), a1_, ar); az = F2(BCH(WZ[4*(c)+1]), a1_, az); an = F2(BCH(WN[4*(c)+1]), a1_, an); \
  ar = F2(BCH(WR[4*(c)+2]), a2_, ar); az = F2(BCH(WZ[4*(c)+2]), a2_, az); an = F2(BCH(WN[4*(c)+2]), a2_, an); \
  ar = F2(BCH(WR[4*(c)+3]), a3_, ar); az = F2(BCH(WZ[4*(c)+3]), a3_, az); an = F2(BCH(WN[4*(c)+3]), a3_, an); }
#define DOT16 \
  DOTC(0) DOTC(1) DOTC(2) DOTC(3) DOTC(4) DOTC(5) DOTC(6) DOTC(7) \
  DOTC(8) DOTC(9) DOTC(10) DOTC(11) DOTC(12) DOTC(13) DOTC(14) DOTC(15)

// deep tail: rows with d >= NBUCK, processed serially per chain
__global__ __launch_bounds__(512, 2) void ktail(const u16* __restrict__ xproj,
                                                float* __restrict__ out,
                                                const u16* __restrict__ WhF,
                                                const unsigned char* __restrict__ dbuf,
                                                const void* __restrict__ bir, const void* __restrict__ biz,
                                                const void* __restrict__ bin_, const void* __restrict__ bhn,
                                                const int* __restrict__ flags) {
  int w = blockIdx.x;
  int tid = threadIdx.x;
  int j = tid >> 1;
  int half = tid & 1;
  bool wf32 = flags[2] != 0;
  __shared__ __align__(16) u16 hsb[256];
  __shared__ unsigned char dcol[1024];
  for (int t = tid; t < 1024; t += 512) dcol[t] = dbuf[(size_t)w * 1024 + t];
  const u16* pr = WhF + (size_t)j * H + half * 128;
  const u16* pz = WhF + (size_t)H * H + (size_t)j * H + half * 128;
  const u16* pn = WhF + (size_t)2 * H * H + (size_t)j * H + half * 128;
  v64u WR, WZ, WN;
  LDWALL(WR, pr)
  LDWALL(WZ, pz)
  LDWALL(WN, pn)
  float vbir = ldf(bir, wf32, j), vbiz = ldf(biz, wf32, j);
  float vbin = ldf(bin_, wf32, j), vbhn = ldf(bhn, wf32, j);
  __syncthreads();
  int prev_t = -99;
  float hreg = 0.0f;
#pragma unroll 1
  for (int t = 0; t < 1024; ++t) {
    int d = dcol[t];
    if (d < NBUCK || d == 255) continue;  // uniform across block
    if (prev_t != t - 1) {
      hreg = out[((size_t)(t - 1) * BA + w) * H + j];
      if (half == 0) { _Float16 hh = (_Float16)hreg; hsb[j] = __builtin_bit_cast(u16, hh); }
      __syncthreads();
    }
    const uint4* h4_ = (const uint4*)(&hsb[half * 128]);
    float ar = 0.0f, az = 0.0f, an = 0.0f;
    DOT16
    ar += __shfl_xor(ar, 1, 64);
    az += __shfl_xor(az, 1, 64);
    an += __shfl_xor(an, 1, 64);
    size_t xb = ((size_t)t * BA + w) * TH + j;
    float r = sigm(bf2f(xproj[xb]) + vbir + ar);
    float z = sigm(bf2f(xproj[xb + H]) + vbiz + az);
    float n = tanh_(bf2f(xproj[xb + 2 * H]) + vbin + r * (an + vbhn));
    float hnew = (1.0f - z) * n + z * hreg;
    if (half == 0) out[((size_t)t * BA + w) * H + j] = hnew;
    __syncthreads();
    if (half == 0) { _Float16 hh = (_Float16)hnew; hsb[j] = __builtin_bit_cast(u16, hh); }
    hreg = hnew;
    prev_t = t;
    __syncthreads();
  }
}

// ---- fallback serial scan (used only when workspace can't hold full xproj) ----
__global__ __launch_bounds__(512, 2) void kscan(
    const u16* __restrict__ xproj, const void* __restrict__ resets,
    const void* __restrict__ h0, float* __restrict__ carry,
    const u16* __restrict__ WhF,
    const void* __restrict__ bir, const void* __restrict__ biz, const void* __restrict__ bin_,
    const void* __restrict__ bhn, float* __restrict__ out, int t0, int Tc,
    const int* __restrict__ flags) {
  int w = blockIdx.x;
  int tid = threadIdx.x;
  int j = tid >> 1;
  int half = tid & 1;
  bool wf32 = flags[2] != 0;
  bool rbyte = flags[1] != 0;
  __shared__ __align__(16) u16 hsb[2][256];
  __shared__ int rstS[1024];

  for (int t = tid; t < Tc; t += 512)
    rstS[t] = ldrst(resets, rbyte, (size_t)(t0 + t) * BA + w);

  const u16* pr = WhF + (size_t)j * H + half * 128;
  const u16* pz = WhF + (size_t)H * H + (size_t)j * H + half * 128;
  const u16* pn = WhF + (size_t)2 * H * H + (size_t)j * H + half * 128;
  v64u WR, WZ, WN;
  LDWALL(WR, pr)
  LDWALL(WZ, pz)
  LDWALL(WN, pn)

  float vbir = ldf(bir, wf32, j), vbiz = ldf(biz, wf32, j);
  float vbin = ldf(bin_, wf32, j), vbhn = ldf(bhn, wf32, j);

  float hreg = (t0 == 0) ? ldf(h0, wf32, (size_t)w * H + j) : carry[(size_t)w * H + j];
  __syncthreads();
  if (rstS[0] != 0) hreg = 0.0f;
  if (half == 0) {
    _Float16 hh = (_Float16)hreg;
    hsb[0][j] = __builtin_bit_cast(u16, hh);
  }
  __syncthreads();

  size_t xb0 = (size_t)w * TH + j;
  u16 cxr = xproj[xb0], cxz = xproj[xb0 + H], cxn = xproj[xb0 + 2 * H];

#pragma unroll 1
  for (int tl = 0; tl < Tc; ++tl) {
    u16 nxr = 0, nxz = 0, nxn = 0;
    if (tl + 1 < Tc) {
      size_t nb = ((size_t)(tl + 1) * BA + w) * TH + j;
      nxr = xproj[nb]; nxz = xproj[nb + H]; nxn = xproj[nb + 2 * H];
    }
    const uint4* h4_ = (const uint4*)(&hsb[tl & 1][half * 128]);
    float ar = 0.0f, az = 0.0f, an = 0.0f;
    DOT16
    ar += __shfl_xor(ar, 1, 64);
    az += __shfl_xor(az, 1, 64);
    an += __shfl_xor(an, 1, 64);
    float r = sigm(bf2f(cxr) + vbir + ar);
    float z = sigm(bf2f(cxz) + vbiz + az);
    float n = tanh_(bf2f(cxn) + vbin + r * (an + vbhn));
    float hnew = (1.0f - z) * n + z * hreg;
    if (half == 0) out[((size_t)(t0 + tl) * BA + w) * H + j] = hnew;

    float hnext = hnew;
    if (tl + 1 < Tc && rstS[tl + 1] != 0) hnext = 0.0f;
    if (half == 0) {
      _Float16 hh = (_Float16)hnext;
      hsb[(tl & 1) ^ 1][j] = __builtin_bit_cast(u16, hh);
    }
    hreg = hnext;
    cxr = nxr; cxz = nxz; cxn = nxn;
    __syncthreads();
  }
  if (half == 0) carry[(size_t)w * H + j] = hreg;
}

extern "C" void kernel_launch(void* const* d_in, const int* in_sizes, int n_in,
                              void* d_out, int out_size, void* d_ws, size_t ws_size,
                              hipStream_t stream) {
  const void* ins = d_in[0];
  const void* resets = d_in[1];
  const void* h0 = d_in[2];
  const void* Wir = d_in[3];
  const void* Wiz = d_in[4];
  const void* Win = d_in[5];
  const void* bir = d_in[6];
  const void* biz = d_in[7];
  const void* bin_ = d_in[8];
  const void* Whr = d_in[9];
  const void* Whz = d_in[10];
  const void* Whn = d_in[11];
  const void* bhn = d_in[12];
  float* out = (float*)d_out;

  // ws: [flags][WT 768KB][carry 128KB][cnt 256B][dbuf 128KB][lists 2MB][WB 768KB][xproj]
  const size_t off_wt = 256;
  const size_t wt_bytes = (size_t)6 * H * H * 2;
  const size_t off_carry = off_wt + wt_bytes;
  const size_t off_cnt = off_carry + (size_t)BA * H * 4;
  const size_t off_dbuf = off_cnt + 256;
  const size_t off_list = off_dbuf + NROWS;
  const size_t off_wb = off_list + (size_t)NBUCK * LCAP * 4;
  const size_t wb_bytes = (size_t)2 * TH * H * 2;  // WiB + WhB
  const size_t off_xproj = off_wb + wb_bytes;
  const size_t chunk_bytes = (size_t)BA * TH * 2;

  int* flags = (int*)d_ws;
  u16* WT = (u16*)((char*)d_ws + off_wt);
  float* carry = (float*)((char*)d_ws + off_carry);
  int* cnt = (int*)((char*)d_ws + off_cnt);
  unsigned char* dbuf = (unsigned char*)((char*)d_ws + off_dbuf);
  u32* list = (u32*)((char*)d_ws + off_list);
  u16* WB = (u16*)((char*)d_ws + off_wb);
  u16* xproj = (u16*)((char*)d_ws + off_xproj);

  kdetect<<<1, 256, 0, stream>>>((const u32*)ins, (const u32*)resets,
                                 (const u32*)Whr, (const u32*)Wir, flags, cnt);
  ktrans<<<dim3(4, 4, 6), 256, 0, stream>>>(Wir, Wiz, Win, Whr, Whz, Whn, WT, flags);
  kswz<<<dim3(96, 2), 256, 0, stream>>>(WT, WB);

  const u16* WiB = WB;
  const u16* WhB = WB + (size_t)NFRAG * 8;
  const u16* WhT = WT + (size_t)3 * H * H;
  if (ws_size >= off_xproj + (size_t)1024 * chunk_bytes) {
    // segment-parallel path: full xproj, then process rows by reset-distance d
    kdlists<<<128, 256, 0, stream>>>(resets, dbuf, cnt, list, flags);
    kgemm<<<1024, 256, 0, stream>>>(ins, 0, WiB, xproj, flags);
    kelem<<<1024, 256, 0, stream>>>(xproj, resets, out, bir, biz, bin_, bhn, flags);
    for (int s = 0; s < NBUCK; ++s)
      kstep<<<1024, 512, 0, stream>>>(xproj, out, h0, WhB, cnt, list + (size_t)s * LCAP,
                                      bir, biz, bin_, bhn, flags, s);
    ktail<<<128, 512, 0, stream>>>(xproj, out, WhT, dbuf, bir, biz, bin_, bhn, flags);
  } else {
    // fallback: chunked serial scan
    int Tc = 1024;
    while (Tc > 1 && off_xproj + (size_t)Tc * chunk_bytes > ws_size) Tc >>= 1;
    int nchunks = 1024 / Tc;
    for (int c = 0; c < nchunks; ++c) {
      int t0 = c * Tc;
      kgemm<<<Tc, 256, 0, stream>>>(ins, t0, WiB, xproj, flags);
      kscan<<<128, 512, 0, stream>>>(xproj, resets, h0, carry, WhT,
                                     bir, biz, bin_, bhn, out, t0, Tc, flags);
    }
  }
}